// Round 17
// baseline (202.301 us; speedup 1.0000x reference)
//
#include <hip/hip_runtime.h>
#include <hip/hip_bf16.h>

#define D768 768

typedef __attribute__((ext_vector_type(8))) short short8;
typedef __attribute__((ext_vector_type(4))) float f32x4;

__device__ __forceinline__ unsigned short f2bf(float f){
  union { float f; unsigned u; } v; v.f = f;
  unsigned r = v.u + 0x7FFFu + ((v.u >> 16) & 1u);
  return (unsigned short)(r >> 16);
}
__device__ __forceinline__ float bf2f(unsigned short u){
  union { unsigned u; float f; } v; v.u = ((unsigned)u) << 16;
  return v.f;
}
// exact-erf GELU via Abramowitz-Stegun 7.1.26 (|eps| <= 1.5e-7), ~13 VALU + exp + rcp
__device__ __forceinline__ float gelu_f(float x){
  float y = fabsf(x) * 0.7071067811865475f;
  float t = __builtin_amdgcn_rcpf(fmaf(0.3275911f, y, 1.0f));
  float p = fmaf(fmaf(fmaf(fmaf(1.061405429f, t, -1.453152027f), t, 1.421413741f),
                      t, -0.284496736f), t, 0.254829592f) * t;
  float e = __expf(-y * y);
  float erf_abs = fmaf(-p, e, 1.0f);
  float erfv = copysignf(erf_abs, x);
  return 0.5f * x * (1.0f + erfv);
}
__device__ __forceinline__ void gload16(const void* g, void* l){
  __builtin_amdgcn_global_load_lds((const __attribute__((address_space(1))) void*)g,
                                   (__attribute__((address_space(3))) void*)l, 16, 0, 0);
}

// ---------- MEGA kernel: init (0..127) + weight transpose (128..2455) +
// target LN (2456..3479, 4 rows/block) + support LN (3480..11671, 4 rows/block).
__global__ __launch_bounds__(256)
void k_mega(const float* __restrict__ target, const float* __restrict__ support,
            const float* __restrict__ t_g, const float* __restrict__ t_b,
            const float* __restrict__ s_g, const float* __restrict__ s_b,
            float* __restrict__ th, unsigned short* __restrict__ gcat,
            unsigned short* __restrict__ sh,
            const float* __restrict__ sw1, const float* __restrict__ gw1,
            unsigned short* __restrict__ WtA, unsigned short* __restrict__ WtB,
            unsigned short* __restrict__ WtG,
            float* __restrict__ scores, const float* __restrict__ sb2,
            float* __restrict__ gacc, const float* __restrict__ gb2,
            const unsigned char* __restrict__ m, int* __restrict__ flag){
  int blk = blockIdx.x;
  int t = threadIdx.x;
  if (blk < 128){
    int i = blk * 256 + t;
    if (i < 32768) scores[i] = sb2[0];
    if (i < 4096)  gacc[i]   = gb2[0];
    if (blk == 0){
      __shared__ int s;
      if (t == 0) s = 0;
      __syncthreads();
      int nz = 0;
      for (int j = t; j < 2048; j += 256) nz += (m[4*j+1] != 0);
      atomicAdd(&s, nz);
      __syncthreads();
      if (t == 0) *flag = (s == 0) ? 1 : 0; // 1 => 4-byte mask elems
    }
    return;
  }
  if (blk < 2456){
    int tile = blk - 128;
    const float* W; unsigned short* Wt; int Kin, Kpad;
    if (tile < 576)      { W = sw1;              Wt = WtA; Kin = 768;  Kpad = 768;  }
    else if (tile < 1152){ W = sw1 + 768ull*768; Wt = WtB; Kin = 768;  Kpad = 768;  tile -= 576; }
    else                 { W = gw1;              Wt = WtG; Kin = 1552; Kpad = 1568; tile -= 1152; }
    int ntk = Kpad >> 5;
    int k0 = (tile % ntk) << 5, n0 = (tile / ntk) << 5;
    __shared__ float ts[32][33];
    int tx = t & 31, ty = t >> 5; // 32x8
    #pragma unroll
    for (int r = 0; r < 4; ++r){
      int k = k0 + ty + r*8;
      ts[ty + r*8][tx] = (k < Kin) ? W[(size_t)k * D768 + n0 + tx] : 0.f;
    }
    __syncthreads();
    #pragma unroll
    for (int r = 0; r < 4; ++r){
      int n = n0 + ty + r*8;
      Wt[(size_t)n * Kpad + k0 + tx] = f2bf(ts[tx][ty + r*8]);
    }
    return;
  }
  // LayerNorm: 1 wave per row, 4 rows per block
  bool isT = blk < 3480;
  int row = (isT ? (blk - 2456) : (blk - 3480)) * 4 + (t >> 6);
  int lane = t & 63;
  const float* xr = (isT ? target : support) + (size_t)row * D768;
  float4 v0 = *(const float4*)(xr + lane*4);
  float4 v1 = *(const float4*)(xr + 256 + lane*4);
  float4 v2 = *(const float4*)(xr + 512 + lane*4);
  float s  = v0.x+v0.y+v0.z+v0.w + v1.x+v1.y+v1.z+v1.w + v2.x+v2.y+v2.z+v2.w;
  float ss = v0.x*v0.x+v0.y*v0.y+v0.z*v0.z+v0.w*v0.w
           + v1.x*v1.x+v1.y*v1.y+v1.z*v1.z+v1.w*v1.w
           + v2.x*v2.x+v2.y*v2.y+v2.z*v2.z+v2.w*v2.w;
  #pragma unroll
  for (int o = 32; o; o >>= 1){ s += __shfl_xor(s, o); ss += __shfl_xor(ss, o); }
  float mean = s * (1.f/768.f);
  float var  = ss * (1.f/768.f) - mean*mean;
  float rstd = rsqrtf(var + 1e-5f);
  const float* gg = isT ? t_g : s_g;
  const float* bb = isT ? t_b : s_b;
  #pragma unroll
  for (int k = 0; k < 3; ++k){
    int c = lane*4 + k*256;
    float4 v = (k==0) ? v0 : (k==1) ? v1 : v2;
    float4 gv = *(const float4*)(gg + c);
    float4 bv = *(const float4*)(bb + c);
    float o0 = (v.x-mean)*rstd*gv.x + bv.x;
    float o1 = (v.y-mean)*rstd*gv.y + bv.y;
    float o2 = (v.z-mean)*rstd*gv.z + bv.z;
    float o3 = (v.w-mean)*rstd*gv.w + bv.w;
    ushort4 ub; ub.x=f2bf(o0); ub.y=f2bf(o1); ub.z=f2bf(o2); ub.w=f2bf(o3);
    if (isT){
      float4 ov; ov.x=o0; ov.y=o1; ov.z=o2; ov.w=o3;
      *(float4*)(th + (size_t)row * D768 + c) = ov;
      *(ushort4*)(gcat + (size_t)row * 1568 + c) = ub;
    } else {
      *(ushort4*)(sh + (size_t)row * D768 + c) = ub;
    }
  }
}

// ---------- 4-wave MFMA GEMM (tproj), 128xBN tile, depth-3 ring ----------
template<int MODE, int BN>
__launch_bounds__(256)
__global__ void k_gemm(const unsigned short* __restrict__ A, int lda,
                       const unsigned short* __restrict__ Bt, int ldb,
                       int ksteps, int ntn,
                       const float* __restrict__ tproj,
                       const float* __restrict__ b1,
                       const float* __restrict__ w2,
                       float* __restrict__ out){
  constexpr int NJ  = BN / 32;
  constexpr int BCH = BN / 64;
  __shared__ __align__(16) unsigned short As[3][128*32];
  __shared__ __align__(16) unsigned short Bs[3][BN*32];
  const int cpx = gridDim.x >> 3;
  const int logical = ((int)blockIdx.x & 7) * cpx + ((int)blockIdx.x >> 3);
  const int m0 = (logical / ntn) * 128, n0 = (logical % ntn) * BN;
  const int t = threadIdx.x, lane = t & 63, w = t >> 6;
  const int wrow = (w >> 1) * 64, wcol = (w & 1) * (BN/2);
  const int lo16 = lane & 15;
  const int hs = ((lane >> 4) ^ ((lo16 >> 1) & 3)) * 8;
  const int crow = lane >> 2;
  const int cseg = (((lane & 3) ^ ((lane >> 3) & 3)) * 8);
  const unsigned short* ga = A  + (size_t)(m0 + w*32 + crow) * lda + cseg;
  const unsigned short* gb = Bt + (size_t)(n0 + w*(BN/4) + crow) * ldb + cseg;
  f32x4 acc[4][NJ] = {};

#define STAGEK(BUF, KS) do {                                                   \
    const unsigned short* gak_ = ga + (size_t)(KS)*32;                         \
    const unsigned short* gbk_ = gb + (size_t)(KS)*32;                         \
    _Pragma("unroll")                                                          \
    for (int c = 0; c < 2; ++c)                                                \
      gload16(gak_ + (size_t)(c*16)*lda, &As[BUF][w*1024 + c*512]);            \
    _Pragma("unroll")                                                          \
    for (int c = 0; c < BCH; ++c)                                              \
      gload16(gbk_ + (size_t)(c*16)*ldb, &Bs[BUF][w*(BN/4)*32 + c*512]);       \
  } while (0)

#define COMPUTEK(BUF) do {                                                     \
    const unsigned short* pa_ = &As[BUF][(wrow + lo16)*32 + hs];               \
    const unsigned short* pb_ = &Bs[BUF][(wcol + lo16)*32 + hs];               \
    short8 af_[4], bf_[NJ];                                                    \
    _Pragma("unroll")                                                          \
    for (int i = 0; i < 4; ++i) af_[i] = *(const short8*)(pa_ + i*16*32);      \
    _Pragma("unroll")                                                          \
    for (int j = 0; j < NJ; ++j) bf_[j] = *(const short8*)(pb_ + j*16*32);     \
    __builtin_amdgcn_s_setprio(1);                                             \
    _Pragma("unroll")                                                          \
    for (int i = 0; i < 4; ++i)                                                \
      _Pragma("unroll")                                                        \
      for (int j = 0; j < NJ; ++j)                                             \
        acc[i][j] = __builtin_amdgcn_mfma_f32_16x16x32_bf16(af_[i], bf_[j], acc[i][j], 0, 0, 0); \
    __builtin_amdgcn_s_setprio(0);                                             \
  } while (0)

#define WAITN(n) asm volatile("s_waitcnt vmcnt(" #n ")" ::: "memory")

  {
    int pro = ksteps < 2 ? ksteps : 2;
    for (int p = 0; p < pro; ++p) STAGEK(p, p);
  }
  for (int ks = 0; ks < ksteps; ++ks){
    int rem = ksteps - ks;
    if (rem >= 2){ if constexpr (BCH == 2) WAITN(4); else WAITN(3); }
    else WAITN(0);
    __builtin_amdgcn_s_barrier();
    __builtin_amdgcn_sched_barrier(0);
    if (ks + 2 < ksteps) STAGEK((ks + 2) % 3, ks + 2);
    COMPUTEK(ks % 3);
  }
#undef STAGEK
#undef COMPUTEK
#undef WAITN

  if (MODE == 0){
    #pragma unroll
    for (int i = 0; i < 4; ++i)
      #pragma unroll
      for (int reg = 0; reg < 4; ++reg){
        int row = m0 + wrow + i*16 + ((lane >> 4) << 2) + reg;
        float* orow = out + (size_t)row * D768 + n0 + wcol + (lane & 15);
        #pragma unroll
        for (int j = 0; j < NJ; ++j) orow[j*16] = acc[i][j][reg];
      }
  } else {
    #pragma unroll
    for (int i = 0; i < 4; ++i)
      #pragma unroll
      for (int reg = 0; reg < 4; ++reg){
        int row = m0 + wrow + i*16 + ((lane >> 4) << 2) + reg;
        float contrib = 0.f;
        #pragma unroll
        for (int j = 0; j < NJ; ++j){
          int n = n0 + wcol + j*16 + (lane & 15);
          float v = acc[i][j][reg] + b1[n];
          contrib += gelu_f(v) * w2[n];
        }
        for (int o = 8; o; o >>= 1) contrib += __shfl_xor(contrib, o);
        if ((lane & 15) == 0) atomicAdd(&out[row], contrib);
      }
  }
}

// ---------- 8-phase MFMA GEMM (score), 256x256 tile, BK=64, 2-dbuf x 2-kslot-half ----------
// T3+T4 template: per K-tile 4 phases (s,rh); each phase {8 ds_read || stage 1 half of
// tile t+1 into other buf} -> barrier -> lgkmcnt(0) -> setprio(1) 16 MFMA setprio(0)
// -> [RH==1: vmcnt(4), tail vmcnt(0)] -> barrier.
// Halves FIFO order Ah0,Bh0,Ah1,Bh1: consumed 4 phases after issue, 2 loads/thread/half
// -> vmcnt(4) retires exactly the pair needed by the next two phases.
// WAR: stage targets buf ^1, whose last reader passed >=2 barriers earlier.
// Swizzle: write side pre-swizzles global seg (cseg), read side hs — same involution.
__launch_bounds__(512)
__global__ void k_score(const unsigned short* __restrict__ A, int lda,
                        const unsigned short* __restrict__ Bt, int ldb,
                        int ntn,
                        const float* __restrict__ tproj,
                        const float* __restrict__ b1,
                        const float* __restrict__ w2,
                        float* __restrict__ out){
  __shared__ __align__(16) unsigned short Ah[2][2][256*32];
  __shared__ __align__(16) unsigned short Bh[2][2][256*32];
  const int cpx = gridDim.x >> 3;
  const int logical = ((int)blockIdx.x & 7) * cpx + ((int)blockIdx.x >> 3);
  const int m0 = (logical / ntn) * 256, n0 = (logical % ntn) * 256;
  const int t = threadIdx.x, lane = t & 63, w = t >> 6; // 8 waves: 2M x 4N
  const int wr = w >> 2, wc = w & 3;                    // wave out: 128 x 64
  const int lo16 = lane & 15;
  const int hs = ((lane >> 4) ^ ((lo16 >> 1) & 3)) * 8;      // read-side seg swizzle
  const int cseg = (((lane & 3) ^ ((lane >> 3) & 3)) * 8);   // write-side (global) swizzle
  const unsigned short* ga = A  + (size_t)(m0 + w*32 + (lane >> 2)) * lda + cseg;
  const unsigned short* gb = Bt + (size_t)(n0 + w*32 + (lane >> 2)) * ldb + cseg;
  f32x4 acc[8][4] = {};

#define PHASE(B, S, RH, T) do {                                                \
    short8 afr[4], bfr[4];                                                     \
    const unsigned short* pa_ = &Ah[B][S][((wr*128 + (RH)*64 + lo16)*32)] + hs;\
    const unsigned short* pb_ = &Bh[B][S][((wc*64 + lo16)*32)] + hs;           \
    _Pragma("unroll")                                                          \
    for (int i = 0; i < 4; ++i) afr[i] = *(const short8*)(pa_ + i*512);        \
    _Pragma("unroll")                                                          \
    for (int j = 0; j < 4; ++j) bfr[j] = *(const short8*)(pb_ + j*512);        \
    if ((T) + 1 < 12){                                                         \
      const unsigned short* gs_ = ((RH) == 0 ? ga : gb) + (size_t)(((T)+1)*64 + (S)*32); \
      unsigned short* ld_ = ((RH) == 0 ? &Ah[(B)^1][S][w*1024] : &Bh[(B)^1][S][w*1024]); \
      gload16(gs_, ld_);                                                       \
      gload16(gs_ + (size_t)16*((RH)==0 ? lda : ldb), ld_ + 512);              \
    }                                                                          \
    __builtin_amdgcn_s_barrier();                                              \
    asm volatile("s_waitcnt lgkmcnt(0)" ::: "memory");                         \
    __builtin_amdgcn_sched_barrier(0);                                         \
    __builtin_amdgcn_s_setprio(1);                                             \
    _Pragma("unroll")                                                          \
    for (int i = 0; i < 4; ++i)                                                \
      _Pragma("unroll")                                                        \
      for (int j = 0; j < 4; ++j)                                              \
        acc[(RH)*4+i][j] = __builtin_amdgcn_mfma_f32_16x16x32_bf16(afr[i], bfr[j], acc[(RH)*4+i][j], 0, 0, 0); \
    __builtin_amdgcn_s_setprio(0);                                             \
    if (RH){                                                                   \
      if ((T) == 11) asm volatile("s_waitcnt vmcnt(0)" ::: "memory");          \
      else           asm volatile("s_waitcnt vmcnt(4)" ::: "memory");          \
    }                                                                          \
    __builtin_amdgcn_s_barrier();                                              \
  } while (0)

  // prologue: tile 0's 4 halves into buf0 (FIFO: Ah0, Bh0, Ah1, Bh1)
  gload16(ga,                       &Ah[0][0][w*1024]);
  gload16(ga + (size_t)16*lda,      &Ah[0][0][w*1024 + 512]);
  gload16(gb,                       &Bh[0][0][w*1024]);
  gload16(gb + (size_t)16*ldb,      &Bh[0][0][w*1024 + 512]);
  gload16(ga + 32,                  &Ah[0][1][w*1024]);
  gload16(ga + 32 + (size_t)16*lda, &Ah[0][1][w*1024 + 512]);
  gload16(gb + 32,                  &Bh[0][1][w*1024]);
  gload16(gb + 32 + (size_t)16*ldb, &Bh[0][1][w*1024 + 512]);
  asm volatile("s_waitcnt vmcnt(4)" ::: "memory");
  __builtin_amdgcn_s_barrier();
  #pragma unroll 1
  for (int tp = 0; tp < 6; ++tp){
    int t0 = 2*tp, t1 = 2*tp + 1;
    PHASE(0,0,0,t0); PHASE(0,0,1,t0); PHASE(0,1,0,t0); PHASE(0,1,1,t0);
    PHASE(1,0,0,t1); PHASE(1,0,1,t1); PHASE(1,1,0,t1); PHASE(1,1,1,t1);
  }
#undef PHASE

  // epilogue: +tproj+b1, exact gelu, *w2, 16-lane reduce, atomicAdd
  float b1v[4], w2v[4];
  #pragma unroll
  for (int j = 0; j < 4; ++j){
    int n = n0 + wc*64 + j*16 + lo16;
    b1v[j] = b1[n]; w2v[j] = w2[n];
  }
  #pragma unroll
  for (int rf = 0; rf < 8; ++rf)
    #pragma unroll
    for (int reg = 0; reg < 4; ++reg){
      int row = m0 + wr*128 + rf*16 + ((lane >> 4) << 2) + reg;
      int trow = ((row >> 13) << 10) | (row & 1023); // (b*8+s)*1024+t -> b*1024+t
      const float* tp = tproj + (size_t)trow * D768;
      float contrib = 0.f;
      #pragma unroll
      for (int j = 0; j < 4; ++j){
        int n = n0 + wc*64 + j*16 + lo16;
        float v = acc[rf][j][reg] + b1v[j] + tp[n];
        contrib += gelu_f(v) * w2v[j];
      }
      for (int o = 8; o; o >>= 1) contrib += __shfl_xor(contrib, o);
      if (lo16 == 0) atomicAdd(&out[row], contrib);
    }
}

// ---------- 8-wave MFMA GEMM (gate), 128x64 tile, depth-3 ring ----------
__launch_bounds__(512)
__global__ void k_gemm8g(const unsigned short* __restrict__ A, int lda,
                         const unsigned short* __restrict__ Bt, int ldb,
                         int ksteps, int ntn,
                         const float* __restrict__ b1,
                         const float* __restrict__ w2,
                         float* __restrict__ out){
  __shared__ __align__(16) unsigned short As[3][128*32];
  __shared__ __align__(16) unsigned short Bs[3][64*32];
  const int cpx = gridDim.x >> 3;
  const int logical = ((int)blockIdx.x & 7) * cpx + ((int)blockIdx.x >> 3);
  const int m0 = (logical / ntn) * 128, n0 = (logical % ntn) * 64;
  const int t = threadIdx.x, lane = t & 63, w = t >> 6; // 8 waves
  const int wrow = (w >> 2) * 64, wcol = (w & 3) * 16;
  const int lo16 = lane & 15;
  const int hs = ((lane >> 4) ^ ((lo16 >> 1) & 3)) * 8;
  const int crow = lane >> 2;
  const int cseg = (((lane & 3) ^ ((lane >> 3) & 3)) * 8);
  const unsigned short* ga = A  + (size_t)(m0 + w*16 + crow) * lda + cseg;
  const unsigned short* gb = Bt + (size_t)(n0 + w*16 + crow) * ldb + cseg; // valid for w<4
  f32x4 acc[4] = {};

#define STAGEK(BUF, KS) do {                                                   \
    gload16(ga + (size_t)(KS)*32, &As[BUF][w*512]);                            \
    if (w < 4) gload16(gb + (size_t)(KS)*32, &Bs[BUF][w*512]);                 \
  } while (0)

#define COMPUTEK(BUF) do {                                                     \
    const unsigned short* pa_ = &As[BUF][(wrow + lo16)*32 + hs];               \
    const unsigned short* pb_ = &Bs[BUF][(wcol + lo16)*32 + hs];               \
    short8 af_[4], bf_;                                                        \
    _Pragma("unroll")                                                          \
    for (int i = 0; i < 4; ++i) af_[i] = *(const short8*)(pa_ + i*16*32);      \
    bf_ = *(const short8*)pb_;                                                 \
    __builtin_amdgcn_s_setprio(1);                                             \
    _Pragma("unroll")                                                          \
    for (int i = 0; i < 4; ++i)                                                \
      acc[i] = __builtin_amdgcn_mfma_f32_16x16x32_bf16(af_[i], bf_, acc[i], 0, 0, 0); \
    __builtin_amdgcn_s_setprio(0);                                             \
  } while (0)

#define WAITN(n) asm volatile("s_waitcnt vmcnt(" #n ")" ::: "memory")

  {
    int pro = ksteps < 2 ? ksteps : 2;
    for (int p = 0; p < pro; ++p) STAGEK(p, p);
  }
  for (int ks = 0; ks < ksteps; ++ks){
    int rem = ksteps - ks;
    if (rem >= 2){ if (w < 4) WAITN(2); else WAITN(1); }
    else WAITN(0);
    __builtin_amdgcn_s_barrier();
    __builtin_amdgcn_sched_barrier(0);
    if (ks + 2 < ksteps) STAGEK((ks + 2) % 3, ks + 2);
    COMPUTEK(ks % 3);
  }
#undef STAGEK
#undef COMPUTEK
#undef WAITN

  #pragma unroll
  for (int i = 0; i < 4; ++i)
    #pragma unroll
    for (int reg = 0; reg < 4; ++reg){
      int row = m0 + wrow + i*16 + ((lane >> 4) << 2) + reg;
      int n = n0 + wcol + lo16;
      float v = acc[i][reg] + b1[n];
      float contrib = gelu_f(v) * w2[n];
      for (int o = 8; o; o >>= 1) contrib += __shfl_xor(contrib, o);
      if (lo16 == 0) atomicAdd(&out[row], contrib);
    }
}

// ---------- masked softmax over S=8 + weighted summary -> gcat[:,768:1568] (bf16) ----------
__global__ void k_smx(const float* __restrict__ scores, const void* __restrict__ maskp,
                      const int* __restrict__ flag, const unsigned short* __restrict__ sh,
                      const float* __restrict__ feat,
                      unsigned short* __restrict__ gcat){
  int bt = blockIdx.x;
  int b = bt >> 10, tt = bt & 1023;
  int t = threadIdx.x; // 192
  int f = *flag;
  float sc[8], mk[8];
  #pragma unroll
  for (int s = 0; s < 8; ++s){
    size_t idx = ((size_t)(b*8 + s) << 10) + tt;
    bool m = f ? (((const int*)maskp)[idx] != 0)
               : (((const unsigned char*)maskp)[idx] != 0);
    mk[s] = m ? 1.f : 0.f;
    float v = scores[idx];
    sc[s] = m ? v : -10000.f;
  }
  float mx = sc[0];
  #pragma unroll
  for (int s = 1; s < 8; ++s) mx = fmaxf(mx, sc[s]);
  float e[8], sum = 0.f;
  #pragma unroll
  for (int s = 0; s < 8; ++s){ e[s] = __expf(sc[s] - mx); sum += e[s]; }
  float inv = 1.f / sum;
  float wv[8], sum2 = 0.f;
  #pragma unroll
  for (int s = 0; s < 8; ++s){ wv[s] = e[s] * inv * mk[s]; sum2 += wv[s]; }
  float inv2 = 1.f / fmaxf(sum2, 1e-8f);
  #pragma unroll
  for (int s = 0; s < 8; ++s) wv[s] *= inv2;
  float a0=0.f, a1=0.f, a2=0.f, a3=0.f;
  #pragma unroll
  for (int s = 0; s < 8; ++s){
    const unsigned short* p = sh + (((size_t)(b*8+s) << 10) + tt) * D768 + t*4;
    ushort4 u = *(const ushort4*)p;
    float ws = wv[s];
    a0 += ws * bf2f(u.x); a1 += ws * bf2f(u.y); a2 += ws * bf2f(u.z); a3 += ws * bf2f(u.w);
  }
  ushort4 ub; ub.x=f2bf(a0); ub.y=f2bf(a1); ub.z=f2bf(a2); ub.w=f2bf(a3);
  *(ushort4*)(gcat + (size_t)bt * 1568 + 768 + t*4) = ub;
  if (t < 8){
    int c = 1536 + t*4;
    float4 fv = make_float4(0.f, 0.f, 0.f, 0.f);
    if (c < 1552) fv = *(const float4*)(feat + (size_t)bt * 16 + (c - 1536));
    ushort4 uf; uf.x=f2bf(fv.x); uf.y=f2bf(fv.y); uf.z=f2bf(fv.z); uf.w=f2bf(fv.w);
    *(ushort4*)(gcat + (size_t)bt * 1568 + c) = uf;
  }
}

// ---------- gate=sigmoid(gacc); x=(2-g)*th+g*summary; out=LN(x). 1 wave/row ----------
__global__ __launch_bounds__(256)
void k_final(const float* __restrict__ th, const unsigned short* __restrict__ gcat,
             const float* __restrict__ gacc, const float* __restrict__ og,
             const float* __restrict__ ob, float* __restrict__ out,
             float* __restrict__ outg){
  int row = blockIdx.x * 4 + (threadIdx.x >> 6);
  int lane = threadIdx.x & 63;
  float gv = 1.f / (1.f + __expf(-gacc[row]));
  if (lane == 0) outg[row] = gv;
  const float* tr = th + (size_t)row * D768;
  const unsigned short* sr = gcat + (size_t)row * 1568 + 768;
  float x[12];
  float s = 0.f, ss = 0.f;
  #pragma unroll
  for (int k = 0; k < 3; ++k){
    int c = lane*4 + k*256;
    float4 tv = *(const float4*)(tr + c);
    ushort4 su = *(const ushort4*)(sr + c);
    float v0 = (2.f-gv)*tv.x + gv*bf2f(su.x);
    float v1 = (2.f-gv)*tv.y + gv*bf2f(su.y);
    float v2 = (2.f-gv)*tv.z + gv*bf2f(su.z);
    float v3 = (2.f-gv)*tv.w + gv*bf2f(su.w);
    x[k*4+0]=v0; x[k*4+1]=v1; x[k*4+2]=v2; x[k*4+3]=v3;
    s += v0+v1+v2+v3;
    ss += v0*v0+v1*v1+v2*v2+v3*v3;
  }
  #pragma unroll
  for (int o = 32; o; o >>= 1){ s += __shfl_xor(s, o); ss += __shfl_xor(ss, o); }
  float mean = s*(1.f/768.f), var = ss*(1.f/768.f)-mean*mean;
  float rstd = rsqrtf(var + 1e-5f);
  #pragma unroll
  for (int k = 0; k < 3; ++k){
    int c = lane*4 + k*256;
    float4 gvv = *(const float4*)(og + c);
    float4 bvv = *(const float4*)(ob + c);
    float4 ov;
    ov.x = (x[k*4+0]-mean)*rstd*gvv.x + bvv.x;
    ov.y = (x[k*4+1]-mean)*rstd*gvv.y + bvv.y;
    ov.z = (x[k*4+2]-mean)*rstd*gvv.z + bvv.z;
    ov.w = (x[k*4+3]-mean)*rstd*gvv.w + bvv.w;
    *(float4*)(out + (size_t)row * D768 + c) = ov;
  }
}

extern "C" void kernel_launch(void* const* d_in, const int* in_sizes, int n_in,
                              void* d_out, int out_size, void* d_ws, size_t ws_size,
                              hipStream_t stream){
  const float* target = (const float*)d_in[0];
  const float* support= (const float*)d_in[1];
  const void*  maskp  = d_in[2];
  const float* feat   = (const float*)d_in[3];
  const float* t_g = (const float*)d_in[4];
  const float* t_b = (const float*)d_in[5];
  const float* s_g = (const float*)d_in[6];
  const float* s_b = (const float*)d_in[7];
  const float* o_g = (const float*)d_in[8];
  const float* o_b = (const float*)d_in[9];
  const float* sw1 = (const float*)d_in[10];
  const float* sb1 = (const float*)d_in[11];
  const float* sw2 = (const float*)d_in[12];
  const float* sb2 = (const float*)d_in[13];
  const float* gw1 = (const float*)d_in[14];
  const float* gb1 = (const float*)d_in[15];
  const float* gw2 = (const float*)d_in[16];
  const float* gb2 = (const float*)d_in[17];

  char* wsb = (char*)d_ws;
  size_t off = 0;
  auto alloc = [&](size_t bytes)->void*{
    void* p = wsb + off; off += (bytes + 255) & ~(size_t)255; return p;
  };
  float* th            = (float*)alloc(4096ull*768*4);
  unsigned short* sh   = (unsigned short*)alloc(32768ull*768*2);
  float* tproj         = (float*)alloc(4096ull*768*4);
  unsigned short* gcat = (unsigned short*)alloc(4096ull*1568*2);
  unsigned short* WtA  = (unsigned short*)alloc(768ull*768*2);
  unsigned short* WtB  = (unsigned short*)alloc(768ull*768*2);
  unsigned short* WtG  = (unsigned short*)alloc(768ull*1568*2);
  float* scores        = (float*)alloc(32768ull*4);
  float* gacc          = (float*)alloc(4096ull*4);
  int*   flag          = (int*)alloc(256);

  float* outm = (float*)d_out;       // (B,T,D)
  float* outg = outm + 4096ull*768;  // (B,T)

  // init + maskdet + weight transposes + target LN + support LN (one launch)
  k_mega<<<11672, 256, 0, stream>>>(target, support, t_g, t_b, s_g, s_b,
                                    th, gcat, sh, sw1, gw1, WtA, WtB, WtG,
                                    scores, sb2, gacc, gb2,
                                    (const unsigned char*)maskp, flag);
  // tproj = th @ W1a   (384 blocks, ntn=12)
  k_gemm<0,64><<<384, 256, 0, stream>>>(gcat, 1568, WtA, 768, 24, 12,
                                        nullptr, nullptr, nullptr, tproj);
  // scores += rowsum(gelu(sh@W1b + tproj + b1) * w2)  (8-phase 256x256, 384 blocks, ntn=3)
  k_score<<<384, 512, 0, stream>>>(sh, 768, WtB, 768, 3,
                                   tproj, sb1, sw2, scores);
  // masked softmax + summary -> gcat[:, 768:1568]
  k_smx<<<4096, 192, 0, stream>>>(scores, maskp, flag, sh, feat, gcat);
  // gate_acc += rowsum(gelu(gcat@gW1 + gb1) * gw2)   (8-wave, 384 blocks, ntn=12)
  k_gemm8g<<<384, 512, 0, stream>>>(gcat, 1568, WtG, 1568, 49, 12,
                                    gb1, gw2, gacc);
  k_final<<<1024, 256, 0, stream>>>(th, gcat, gacc, o_g, o_b, outm, outg);
}

// Round 18
// 171.489 us; speedup vs baseline: 1.1797x; 1.1797x over previous
//
#include <hip/hip_runtime.h>
#include <hip/hip_bf16.h>

#define D768 768

typedef __attribute__((ext_vector_type(8))) short short8;
typedef __attribute__((ext_vector_type(4))) float f32x4;

__device__ __forceinline__ unsigned short f2bf(float f){
  union { float f; unsigned u; } v; v.f = f;
  unsigned r = v.u + 0x7FFFu + ((v.u >> 16) & 1u);
  return (unsigned short)(r >> 16);
}
__device__ __forceinline__ float bf2f(unsigned short u){
  union { unsigned u; float f; } v; v.u = ((unsigned)u) << 16;
  return v.f;
}
// exact-erf GELU via Abramowitz-Stegun 7.1.26 (|eps| <= 1.5e-7), ~13 VALU + exp + rcp
__device__ __forceinline__ float gelu_f(float x){
  float y = fabsf(x) * 0.7071067811865475f;
  float t = __builtin_amdgcn_rcpf(fmaf(0.3275911f, y, 1.0f));
  float p = fmaf(fmaf(fmaf(fmaf(1.061405429f, t, -1.453152027f), t, 1.421413741f),
                      t, -0.284496736f), t, 0.254829592f) * t;
  float e = __expf(-y * y);
  float erf_abs = fmaf(-p, e, 1.0f);
  float erfv = copysignf(erf_abs, x);
  return 0.5f * x * (1.0f + erfv);
}
__device__ __forceinline__ void gload16(const void* g, void* l){
  __builtin_amdgcn_global_load_lds((const __attribute__((address_space(1))) void*)g,
                                   (__attribute__((address_space(3))) void*)l, 16, 0, 0);
}

// ---------- MEGA kernel: init (0..127) + weight transpose (128..2455) +
// target LN (2456..3479, 4 rows/block) + support LN (3480..11671, 4 rows/block).
__global__ __launch_bounds__(256)
void k_mega(const float* __restrict__ target, const float* __restrict__ support,
            const float* __restrict__ t_g, const float* __restrict__ t_b,
            const float* __restrict__ s_g, const float* __restrict__ s_b,
            float* __restrict__ th, unsigned short* __restrict__ gcat,
            unsigned short* __restrict__ sh,
            const float* __restrict__ sw1, const float* __restrict__ gw1,
            unsigned short* __restrict__ WtA, unsigned short* __restrict__ WtB,
            unsigned short* __restrict__ WtG,
            float* __restrict__ scores, const float* __restrict__ sb2,
            float* __restrict__ gacc, const float* __restrict__ gb2,
            const unsigned char* __restrict__ m, int* __restrict__ flag){
  int blk = blockIdx.x;
  int t = threadIdx.x;
  if (blk < 128){
    int i = blk * 256 + t;
    if (i < 32768) scores[i] = sb2[0];
    if (i < 4096)  gacc[i]   = gb2[0];
    if (blk == 0){
      __shared__ int s;
      if (t == 0) s = 0;
      __syncthreads();
      int nz = 0;
      for (int j = t; j < 2048; j += 256) nz += (m[4*j+1] != 0);
      atomicAdd(&s, nz);
      __syncthreads();
      if (t == 0) *flag = (s == 0) ? 1 : 0; // 1 => 4-byte mask elems
    }
    return;
  }
  if (blk < 2456){
    int tile = blk - 128;
    const float* W; unsigned short* Wt; int Kin, Kpad;
    if (tile < 576)      { W = sw1;              Wt = WtA; Kin = 768;  Kpad = 768;  }
    else if (tile < 1152){ W = sw1 + 768ull*768; Wt = WtB; Kin = 768;  Kpad = 768;  tile -= 576; }
    else                 { W = gw1;              Wt = WtG; Kin = 1552; Kpad = 1568; tile -= 1152; }
    int ntk = Kpad >> 5;
    int k0 = (tile % ntk) << 5, n0 = (tile / ntk) << 5;
    __shared__ float ts[32][33];
    int tx = t & 31, ty = t >> 5; // 32x8
    #pragma unroll
    for (int r = 0; r < 4; ++r){
      int k = k0 + ty + r*8;
      ts[ty + r*8][tx] = (k < Kin) ? W[(size_t)k * D768 + n0 + tx] : 0.f;
    }
    __syncthreads();
    #pragma unroll
    for (int r = 0; r < 4; ++r){
      int n = n0 + ty + r*8;
      Wt[(size_t)n * Kpad + k0 + tx] = f2bf(ts[tx][ty + r*8]);
    }
    return;
  }
  // LayerNorm: 1 wave per row, 4 rows per block
  bool isT = blk < 3480;
  int row = (isT ? (blk - 2456) : (blk - 3480)) * 4 + (t >> 6);
  int lane = t & 63;
  const float* xr = (isT ? target : support) + (size_t)row * D768;
  float4 v0 = *(const float4*)(xr + lane*4);
  float4 v1 = *(const float4*)(xr + 256 + lane*4);
  float4 v2 = *(const float4*)(xr + 512 + lane*4);
  float s  = v0.x+v0.y+v0.z+v0.w + v1.x+v1.y+v1.z+v1.w + v2.x+v2.y+v2.z+v2.w;
  float ss = v0.x*v0.x+v0.y*v0.y+v0.z*v0.z+v0.w*v0.w
           + v1.x*v1.x+v1.y*v1.y+v1.z*v1.z+v1.w*v1.w
           + v2.x*v2.x+v2.y*v2.y+v2.z*v2.z+v2.w*v2.w;
  #pragma unroll
  for (int o = 32; o; o >>= 1){ s += __shfl_xor(s, o); ss += __shfl_xor(ss, o); }
  float mean = s * (1.f/768.f);
  float var  = ss * (1.f/768.f) - mean*mean;
  float rstd = rsqrtf(var + 1e-5f);
  const float* gg = isT ? t_g : s_g;
  const float* bb = isT ? t_b : s_b;
  #pragma unroll
  for (int k = 0; k < 3; ++k){
    int c = lane*4 + k*256;
    float4 v = (k==0) ? v0 : (k==1) ? v1 : v2;
    float4 gv = *(const float4*)(gg + c);
    float4 bv = *(const float4*)(bb + c);
    float o0 = (v.x-mean)*rstd*gv.x + bv.x;
    float o1 = (v.y-mean)*rstd*gv.y + bv.y;
    float o2 = (v.z-mean)*rstd*gv.z + bv.z;
    float o3 = (v.w-mean)*rstd*gv.w + bv.w;
    ushort4 ub; ub.x=f2bf(o0); ub.y=f2bf(o1); ub.z=f2bf(o2); ub.w=f2bf(o3);
    if (isT){
      float4 ov; ov.x=o0; ov.y=o1; ov.z=o2; ov.w=o3;
      *(float4*)(th + (size_t)row * D768 + c) = ov;
      *(ushort4*)(gcat + (size_t)row * 1568 + c) = ub;
    } else {
      *(ushort4*)(sh + (size_t)row * D768 + c) = ub;
    }
  }
}

// ---------- 4-wave MFMA GEMM (tproj), 128xBN tile, depth-3 ring ----------
template<int MODE, int BN>
__launch_bounds__(256)
__global__ void k_gemm(const unsigned short* __restrict__ A, int lda,
                       const unsigned short* __restrict__ Bt, int ldb,
                       int ksteps, int ntn,
                       const float* __restrict__ tproj,
                       const float* __restrict__ b1,
                       const float* __restrict__ w2,
                       float* __restrict__ out){
  constexpr int NJ  = BN / 32;
  constexpr int BCH = BN / 64;
  __shared__ __align__(16) unsigned short As[3][128*32];
  __shared__ __align__(16) unsigned short Bs[3][BN*32];
  const int cpx = gridDim.x >> 3;
  const int logical = ((int)blockIdx.x & 7) * cpx + ((int)blockIdx.x >> 3);
  const int m0 = (logical / ntn) * 128, n0 = (logical % ntn) * BN;
  const int t = threadIdx.x, lane = t & 63, w = t >> 6;
  const int wrow = (w >> 1) * 64, wcol = (w & 1) * (BN/2);
  const int lo16 = lane & 15;
  const int hs = ((lane >> 4) ^ ((lo16 >> 1) & 3)) * 8;
  const int crow = lane >> 2;
  const int cseg = (((lane & 3) ^ ((lane >> 3) & 3)) * 8);
  const unsigned short* ga = A  + (size_t)(m0 + w*32 + crow) * lda + cseg;
  const unsigned short* gb = Bt + (size_t)(n0 + w*(BN/4) + crow) * ldb + cseg;
  f32x4 acc[4][NJ] = {};

#define STAGEK(BUF, KS) do {                                                   \
    const unsigned short* gak_ = ga + (size_t)(KS)*32;                         \
    const unsigned short* gbk_ = gb + (size_t)(KS)*32;                         \
    _Pragma("unroll")                                                          \
    for (int c = 0; c < 2; ++c)                                                \
      gload16(gak_ + (size_t)(c*16)*lda, &As[BUF][w*1024 + c*512]);            \
    _Pragma("unroll")                                                          \
    for (int c = 0; c < BCH; ++c)                                              \
      gload16(gbk_ + (size_t)(c*16)*ldb, &Bs[BUF][w*(BN/4)*32 + c*512]);       \
  } while (0)

#define COMPUTEK(BUF) do {                                                     \
    const unsigned short* pa_ = &As[BUF][(wrow + lo16)*32 + hs];               \
    const unsigned short* pb_ = &Bs[BUF][(wcol + lo16)*32 + hs];               \
    short8 af_[4], bf_[NJ];                                                    \
    _Pragma("unroll")                                                          \
    for (int i = 0; i < 4; ++i) af_[i] = *(const short8*)(pa_ + i*16*32);      \
    _Pragma("unroll")                                                          \
    for (int j = 0; j < NJ; ++j) bf_[j] = *(const short8*)(pb_ + j*16*32);     \
    __builtin_amdgcn_s_setprio(1);                                             \
    _Pragma("unroll")                                                          \
    for (int i = 0; i < 4; ++i)                                                \
      _Pragma("unroll")                                                        \
      for (int j = 0; j < NJ; ++j)                                             \
        acc[i][j] = __builtin_amdgcn_mfma_f32_16x16x32_bf16(af_[i], bf_[j], acc[i][j], 0, 0, 0); \
    __builtin_amdgcn_s_setprio(0);                                             \
  } while (0)

#define WAITN(n) asm volatile("s_waitcnt vmcnt(" #n ")" ::: "memory")

  {
    int pro = ksteps < 2 ? ksteps : 2;
    for (int p = 0; p < pro; ++p) STAGEK(p, p);
  }
  for (int ks = 0; ks < ksteps; ++ks){
    int rem = ksteps - ks;
    if (rem >= 2){ if constexpr (BCH == 2) WAITN(4); else WAITN(3); }
    else WAITN(0);
    __builtin_amdgcn_s_barrier();
    __builtin_amdgcn_sched_barrier(0);
    if (ks + 2 < ksteps) STAGEK((ks + 2) % 3, ks + 2);
    COMPUTEK(ks % 3);
  }
#undef STAGEK
#undef COMPUTEK
#undef WAITN

  if (MODE == 0){
    #pragma unroll
    for (int i = 0; i < 4; ++i)
      #pragma unroll
      for (int reg = 0; reg < 4; ++reg){
        int row = m0 + wrow + i*16 + ((lane >> 4) << 2) + reg;
        float* orow = out + (size_t)row * D768 + n0 + wcol + (lane & 15);
        #pragma unroll
        for (int j = 0; j < NJ; ++j) orow[j*16] = acc[i][j][reg];
      }
  } else {
    #pragma unroll
    for (int i = 0; i < 4; ++i)
      #pragma unroll
      for (int reg = 0; reg < 4; ++reg){
        int row = m0 + wrow + i*16 + ((lane >> 4) << 2) + reg;
        const float* tp = nullptr;
        if (MODE == 1){
          int trow = ((row >> 13) << 10) | (row & 1023);
          tp = tproj + (size_t)trow * D768;
        }
        float contrib = 0.f;
        #pragma unroll
        for (int j = 0; j < NJ; ++j){
          int n = n0 + wcol + j*16 + (lane & 15);
          float v = acc[i][j][reg] + b1[n];
          if (MODE == 1) v += tp[n];
          contrib += gelu_f(v) * w2[n];
        }
        for (int o = 8; o; o >>= 1) contrib += __shfl_xor(contrib, o);
        if ((lane & 15) == 0) atomicAdd(&out[row], contrib);
      }
  }
}

// ---------- 8-wave MFMA GEMM (score), 256x128 tile, depth-3 ring ----------
// Wave grid 4M x 2N: each wave 64x64 (4x4 frags) -> 8 ds_reads per 16 MFMA.
// LDS 3x24KB=72KB -> 2 blocks/CU. Stage: 2 A-chunks + 1 B-chunk per wave (L=3).
// One barrier per K-step (WAR-safe), counted vmcnt, both-sides segment swizzle,
// XCD-aware block swizzle. Best measured score-GEMM configuration (R16: 71.3us).
__launch_bounds__(512)
__global__ void k_gemm8(const unsigned short* __restrict__ A, int lda,
                        const unsigned short* __restrict__ Bt, int ldb,
                        int ksteps, int ntn,
                        const float* __restrict__ tproj,
                        const float* __restrict__ b1,
                        const float* __restrict__ w2,
                        float* __restrict__ out){
  __shared__ __align__(16) unsigned short As[3][256*32];
  __shared__ __align__(16) unsigned short Bs[3][128*32];
  const int cpx = gridDim.x >> 3;
  const int logical = ((int)blockIdx.x & 7) * cpx + ((int)blockIdx.x >> 3);
  const int m0 = (logical / ntn) * 256, n0 = (logical % ntn) * 128;
  const int t = threadIdx.x, lane = t & 63, w = t >> 6; // 8 waves, 4M x 2N
  const int wrow = (w >> 1) * 64, wcol = (w & 1) * 64;
  const int lo16 = lane & 15;
  const int hs = ((lane >> 4) ^ ((lo16 >> 1) & 3)) * 8;
  const int crow = lane >> 2;
  const int cseg = (((lane & 3) ^ ((lane >> 3) & 3)) * 8);
  const unsigned short* ga = A  + (size_t)(m0 + w*32 + crow) * lda + cseg;
  const unsigned short* gb = Bt + (size_t)(n0 + w*16 + crow) * ldb + cseg;
  f32x4 acc[4][4] = {};

#define STAGEK(BUF, KS) do {                                                   \
    const unsigned short* gak_ = ga + (size_t)(KS)*32;                         \
    gload16(gak_,                    &As[BUF][w*1024]);                        \
    gload16(gak_ + (size_t)16*lda,   &As[BUF][w*1024 + 512]);                  \
    gload16(gb + (size_t)(KS)*32,    &Bs[BUF][w*512]);                         \
  } while (0)

#define COMPUTEK(BUF) do {                                                     \
    const unsigned short* pa_ = &As[BUF][(wrow + lo16)*32 + hs];               \
    const unsigned short* pb_ = &Bs[BUF][(wcol + lo16)*32 + hs];               \
    short8 af_[4], bf_[4];                                                     \
    _Pragma("unroll")                                                          \
    for (int i = 0; i < 4; ++i) af_[i] = *(const short8*)(pa_ + i*16*32);      \
    _Pragma("unroll")                                                          \
    for (int j = 0; j < 4; ++j) bf_[j] = *(const short8*)(pb_ + j*16*32);      \
    __builtin_amdgcn_s_setprio(1);                                             \
    _Pragma("unroll")                                                          \
    for (int i = 0; i < 4; ++i)                                                \
      _Pragma("unroll")                                                        \
      for (int j = 0; j < 4; ++j)                                              \
        acc[i][j] = __builtin_amdgcn_mfma_f32_16x16x32_bf16(af_[i], bf_[j], acc[i][j], 0, 0, 0); \
    __builtin_amdgcn_s_setprio(0);                                             \
  } while (0)

#define WAITN(n) asm volatile("s_waitcnt vmcnt(" #n ")" ::: "memory")

  {
    int pro = ksteps < 2 ? ksteps : 2;
    for (int p = 0; p < pro; ++p) STAGEK(p, p);
  }
  for (int ks = 0; ks < ksteps; ++ks){
    int rem = ksteps - ks;
    if (rem >= 2) WAITN(3);
    else WAITN(0);
    __builtin_amdgcn_s_barrier();
    __builtin_amdgcn_sched_barrier(0);
    if (ks + 2 < ksteps) STAGEK((ks + 2) % 3, ks + 2);
    COMPUTEK(ks % 3);
  }
#undef STAGEK
#undef COMPUTEK
#undef WAITN

  // epilogue: hoist b1/w2 (4 cols per thread), then per-row tproj + gelu + reduce
  float b1v[4], w2v[4];
  #pragma unroll
  for (int j = 0; j < 4; ++j){
    int n = n0 + wcol + j*16 + lo16;
    b1v[j] = b1[n]; w2v[j] = w2[n];
  }
  #pragma unroll
  for (int i = 0; i < 4; ++i)
    #pragma unroll
    for (int reg = 0; reg < 4; ++reg){
      int row = m0 + wrow + i*16 + ((lane >> 4) << 2) + reg;
      int trow = ((row >> 13) << 10) | (row & 1023);
      const float* tp = tproj + (size_t)trow * D768;
      float contrib = 0.f;
      #pragma unroll
      for (int j = 0; j < 4; ++j){
        int n = n0 + wcol + j*16 + lo16;
        float v = acc[i][j][reg] + b1v[j] + tp[n];
        contrib += gelu_f(v) * w2v[j];
      }
      for (int o = 8; o; o >>= 1) contrib += __shfl_xor(contrib, o);
      if (lo16 == 0) atomicAdd(&out[row], contrib);
    }
}

// ---------- 8-wave MFMA GEMM (gate), 128x64 tile, depth-3 ring ----------
__launch_bounds__(512)
__global__ void k_gemm8g(const unsigned short* __restrict__ A, int lda,
                         const unsigned short* __restrict__ Bt, int ldb,
                         int ksteps, int ntn,
                         const float* __restrict__ b1,
                         const float* __restrict__ w2,
                         float* __restrict__ out){
  __shared__ __align__(16) unsigned short As[3][128*32];
  __shared__ __align__(16) unsigned short Bs[3][64*32];
  const int cpx = gridDim.x >> 3;
  const int logical = ((int)blockIdx.x & 7) * cpx + ((int)blockIdx.x >> 3);
  const int m0 = (logical / ntn) * 128, n0 = (logical % ntn) * 64;
  const int t = threadIdx.x, lane = t & 63, w = t >> 6; // 8 waves
  const int wrow = (w >> 2) * 64, wcol = (w & 3) * 16;
  const int lo16 = lane & 15;
  const int hs = ((lane >> 4) ^ ((lo16 >> 1) & 3)) * 8;
  const int crow = lane >> 2;
  const int cseg = (((lane & 3) ^ ((lane >> 3) & 3)) * 8);
  const unsigned short* ga = A  + (size_t)(m0 + w*16 + crow) * lda + cseg;
  const unsigned short* gb = Bt + (size_t)(n0 + w*16 + crow) * ldb + cseg; // valid for w<4
  f32x4 acc[4] = {};

#define STAGEK(BUF, KS) do {                                                   \
    gload16(ga + (size_t)(KS)*32, &As[BUF][w*512]);                            \
    if (w < 4) gload16(gb + (size_t)(KS)*32, &Bs[BUF][w*512]);                 \
  } while (0)

#define COMPUTEK(BUF) do {                                                     \
    const unsigned short* pa_ = &As[BUF][(wrow + lo16)*32 + hs];               \
    const unsigned short* pb_ = &Bs[BUF][(wcol + lo16)*32 + hs];               \
    short8 af_[4], bf_;                                                        \
    _Pragma("unroll")                                                          \
    for (int i = 0; i < 4; ++i) af_[i] = *(const short8*)(pa_ + i*16*32);      \
    bf_ = *(const short8*)pb_;                                                 \
    __builtin_amdgcn_s_setprio(1);                                             \
    _Pragma("unroll")                                                          \
    for (int i = 0; i < 4; ++i)                                                \
      acc[i] = __builtin_amdgcn_mfma_f32_16x16x32_bf16(af_[i], bf_, acc[i], 0, 0, 0); \
    __builtin_amdgcn_s_setprio(0);                                             \
  } while (0)

#define WAITN(n) asm volatile("s_waitcnt vmcnt(" #n ")" ::: "memory")

  {
    int pro = ksteps < 2 ? ksteps : 2;
    for (int p = 0; p < pro; ++p) STAGEK(p, p);
  }
  for (int ks = 0; ks < ksteps; ++ks){
    int rem = ksteps - ks;
    if (rem >= 2){ if (w < 4) WAITN(2); else WAITN(1); }
    else WAITN(0);
    __builtin_amdgcn_s_barrier();
    __builtin_amdgcn_sched_barrier(0);
    if (ks + 2 < ksteps) STAGEK((ks + 2) % 3, ks + 2);
    COMPUTEK(ks % 3);
  }
#undef STAGEK
#undef COMPUTEK
#undef WAITN

  #pragma unroll
  for (int i = 0; i < 4; ++i)
    #pragma unroll
    for (int reg = 0; reg < 4; ++reg){
      int row = m0 + wrow + i*16 + ((lane >> 4) << 2) + reg;
      int n = n0 + wcol + lo16;
      float v = acc[i][reg] + b1[n];
      float contrib = gelu_f(v) * w2[n];
      for (int o = 8; o; o >>= 1) contrib += __shfl_xor(contrib, o);
      if (lo16 == 0) atomicAdd(&out[row], contrib);
    }
}

// ---------- masked softmax over S=8 + weighted summary -> gcat[:,768:1568] (bf16) ----------
__global__ void k_smx(const float* __restrict__ scores, const void* __restrict__ maskp,
                      const int* __restrict__ flag, const unsigned short* __restrict__ sh,
                      const float* __restrict__ feat,
                      unsigned short* __restrict__ gcat){
  int bt = blockIdx.x;
  int b = bt >> 10, tt = bt & 1023;
  int t = threadIdx.x; // 192
  int f = *flag;
  float sc[8], mk[8];
  #pragma unroll
  for (int s = 0; s < 8; ++s){
    size_t idx = ((size_t)(b*8 + s) << 10) + tt;
    bool m = f ? (((const int*)maskp)[idx] != 0)
               : (((const unsigned char*)maskp)[idx] != 0);
    mk[s] = m ? 1.f : 0.f;
    float v = scores[idx];
    sc[s] = m ? v : -10000.f;
  }
  float mx = sc[0];
  #pragma unroll
  for (int s = 1; s < 8; ++s) mx = fmaxf(mx, sc[s]);
  float e[8], sum = 0.f;
  #pragma unroll
  for (int s = 0; s < 8; ++s){ e[s] = __expf(sc[s] - mx); sum += e[s]; }
  float inv = 1.f / sum;
  float wv[8], sum2 = 0.f;
  #pragma unroll
  for (int s = 0; s < 8; ++s){ wv[s] = e[s] * inv * mk[s]; sum2 += wv[s]; }
  float inv2 = 1.f / fmaxf(sum2, 1e-8f);
  #pragma unroll
  for (int s = 0; s < 8; ++s) wv[s] *= inv2;
  float a0=0.f, a1=0.f, a2=0.f, a3=0.f;
  #pragma unroll
  for (int s = 0; s < 8; ++s){
    const unsigned short* p = sh + (((size_t)(b*8+s) << 10) + tt) * D768 + t*4;
    ushort4 u = *(const ushort4*)p;
    float ws = wv[s];
    a0 += ws * bf2f(u.x); a1 += ws * bf2f(u.y); a2 += ws * bf2f(u.z); a3 += ws * bf2f(u.w);
  }
  ushort4 ub; ub.x=f2bf(a0); ub.y=f2bf(a1); ub.z=f2bf(a2); ub.w=f2bf(a3);
  *(ushort4*)(gcat + (size_t)bt * 1568 + 768 + t*4) = ub;
  if (t < 8){
    int c = 1536 + t*4;
    float4 fv = make_float4(0.f, 0.f, 0.f, 0.f);
    if (c < 1552) fv = *(const float4*)(feat + (size_t)bt * 16 + (c - 1536));
    ushort4 uf; uf.x=f2bf(fv.x); uf.y=f2bf(fv.y); uf.z=f2bf(fv.z); uf.w=f2bf(fv.w);
    *(ushort4*)(gcat + (size_t)bt * 1568 + c) = uf;
  }
}

// ---------- gate=sigmoid(gacc); x=(2-g)*th+g*summary; out=LN(x). 1 wave/row ----------
__global__ __launch_bounds__(256)
void k_final(const float* __restrict__ th, const unsigned short* __restrict__ gcat,
             const float* __restrict__ gacc, const float* __restrict__ og,
             const float* __restrict__ ob, float* __restrict__ out,
             float* __restrict__ outg){
  int row = blockIdx.x * 4 + (threadIdx.x >> 6);
  int lane = threadIdx.x & 63;
  float gv = 1.f / (1.f + __expf(-gacc[row]));
  if (lane == 0) outg[row] = gv;
  const float* tr = th + (size_t)row * D768;
  const unsigned short* sr = gcat + (size_t)row * 1568 + 768;
  float x[12];
  float s = 0.f, ss = 0.f;
  #pragma unroll
  for (int k = 0; k < 3; ++k){
    int c = lane*4 + k*256;
    float4 tv = *(const float4*)(tr + c);
    ushort4 su = *(const ushort4*)(sr + c);
    float v0 = (2.f-gv)*tv.x + gv*bf2f(su.x);
    float v1 = (2.f-gv)*tv.y + gv*bf2f(su.y);
    float v2 = (2.f-gv)*tv.z + gv*bf2f(su.z);
    float v3 = (2.f-gv)*tv.w + gv*bf2f(su.w);
    x[k*4+0]=v0; x[k*4+1]=v1; x[k*4+2]=v2; x[k*4+3]=v3;
    s += v0+v1+v2+v3;
    ss += v0*v0+v1*v1+v2*v2+v3*v3;
  }
  #pragma unroll
  for (int o = 32; o; o >>= 1){ s += __shfl_xor(s, o); ss += __shfl_xor(ss, o); }
  float mean = s*(1.f/768.f), var = ss*(1.f/768.f)-mean*mean;
  float rstd = rsqrtf(var + 1e-5f);
  #pragma unroll
  for (int k = 0; k < 3; ++k){
    int c = lane*4 + k*256;
    float4 gvv = *(const float4*)(og + c);
    float4 bvv = *(const float4*)(ob + c);
    float4 ov;
    ov.x = (x[k*4+0]-mean)*rstd*gvv.x + bvv.x;
    ov.y = (x[k*4+1]-mean)*rstd*gvv.y + bvv.y;
    ov.z = (x[k*4+2]-mean)*rstd*gvv.z + bvv.z;
    ov.w = (x[k*4+3]-mean)*rstd*gvv.w + bvv.w;
    *(float4*)(out + (size_t)row * D768 + c) = ov;
  }
}

extern "C" void kernel_launch(void* const* d_in, const int* in_sizes, int n_in,
                              void* d_out, int out_size, void* d_ws, size_t ws_size,
                              hipStream_t stream){
  const float* target = (const float*)d_in[0];
  const float* support= (const float*)d_in[1];
  const void*  maskp  = d_in[2];
  const float* feat   = (const float*)d_in[3];
  const float* t_g = (const float*)d_in[4];
  const float* t_b = (const float*)d_in[5];
  const float* s_g = (const float*)d_in[6];
  const float* s_b = (const float*)d_in[7];
  const float* o_g = (const float*)d_in[8];
  const float* o_b = (const float*)d_in[9];
  const float* sw1 = (const float*)d_in[10];
  const float* sb1 = (const float*)d_in[11];
  const float* sw2 = (const float*)d_in[12];
  const float* sb2 = (const float*)d_in[13];
  const float* gw1 = (const float*)d_in[14];
  const float* gb1 = (const float*)d_in[15];
  const float* gw2 = (const float*)d_in[16];
  const float* gb2 = (const float*)d_in[17];

  char* wsb = (char*)d_ws;
  size_t off = 0;
  auto alloc = [&](size_t bytes)->void*{
    void* p = wsb + off; off += (bytes + 255) & ~(size_t)255; return p;
  };
  float* th            = (float*)alloc(4096ull*768*4);
  unsigned short* sh   = (unsigned short*)alloc(32768ull*768*2);
  float* tproj         = (float*)alloc(4096ull*768*4);
  unsigned short* gcat = (unsigned short*)alloc(4096ull*1568*2);
  unsigned short* WtA  = (unsigned short*)alloc(768ull*768*2);
  unsigned short* WtB  = (unsigned short*)alloc(768ull*768*2);
  unsigned short* WtG  = (unsigned short*)alloc(768ull*1568*2);
  float* scores        = (float*)alloc(32768ull*4);
  float* gacc          = (float*)alloc(4096ull*4);
  int*   flag          = (int*)alloc(256);

  float* outm = (float*)d_out;       // (B,T,D)
  float* outg = outm + 4096ull*768;  // (B,T)

  // init + maskdet + weight transposes + target LN + support LN (one launch)
  k_mega<<<11672, 256, 0, stream>>>(target, support, t_g, t_b, s_g, s_b,
                                    th, gcat, sh, sw1, gw1, WtA, WtB, WtG,
                                    scores, sb2, gacc, gb2,
                                    (const unsigned char*)maskp, flag);
  // tproj = th @ W1a   (384 blocks, ntn=12)
  k_gemm<0,64><<<384, 256, 0, stream>>>(gcat, 1568, WtA, 768, 24, 12,
                                        nullptr, nullptr, nullptr, tproj);
  // scores += rowsum(gelu(sh@W1b + tproj + b1) * w2)   (256x128 tile, 768 blocks, ntn=6)
  k_gemm8<<<768, 512, 0, stream>>>(sh, 768, WtB, 768, 24, 6,
                                   tproj, sb1, sw2, scores);
  // masked softmax + summary -> gcat[:, 768:1568]
  k_smx<<<4096, 192, 0, stream>>>(scores, maskp, flag, sh, feat, gcat);
  // gate_acc += rowsum(gelu(gcat@gW1 + gb1) * gw2)   (8-wave, 384 blocks, ntn=12)
  k_gemm8g<<<384, 512, 0, stream>>>(gcat, 1568, WtG, 1568, 49, 12,
                                    gb1, gw2, gacc);
  k_final<<<1024, 256, 0, stream>>>(th, gcat, gacc, o_g, o_b, outm, outg);
}

// Round 19
// 160.888 us; speedup vs baseline: 1.2574x; 1.0659x over previous
//
#include <hip/hip_runtime.h>
#include <hip/hip_bf16.h>

#define D768 768

typedef __attribute__((ext_vector_type(8))) short short8;
typedef __attribute__((ext_vector_type(4))) float f32x4;

__device__ __forceinline__ unsigned short f2bf(float f){
  union { float f; unsigned u; } v; v.f = f;
  unsigned r = v.u + 0x7FFFu + ((v.u >> 16) & 1u);
  return (unsigned short)(r >> 16);
}
__device__ __forceinline__ float bf2f(unsigned short u){
  union { unsigned u; float f; } v; v.u = ((unsigned)u) << 16;
  return v.f;
}
// exact-erf GELU via Abramowitz-Stegun 7.1.26 (|eps| <= 1.5e-7), ~13 VALU + exp + rcp
__device__ __forceinline__ float gelu_f(float x){
  float y = fabsf(x) * 0.7071067811865475f;
  float t = __builtin_amdgcn_rcpf(fmaf(0.3275911f, y, 1.0f));
  float p = fmaf(fmaf(fmaf(fmaf(1.061405429f, t, -1.453152027f), t, 1.421413741f),
                      t, -0.284496736f), t, 0.254829592f) * t;
  float e = __expf(-y * y);
  float erf_abs = fmaf(-p, e, 1.0f);
  float erfv = copysignf(erf_abs, x);
  return 0.5f * x * (1.0f + erfv);
}
__device__ __forceinline__ void gload16(const void* g, void* l){
  __builtin_amdgcn_global_load_lds((const __attribute__((address_space(1))) void*)g,
                                   (__attribute__((address_space(3))) void*)l, 16, 0, 0);
}

// ---------- PRE kernel: init (0..127) + weight transpose (128..2455) +
// target LN (2456..3479, 4 rows/block, 1 wave/row) ----------
__global__ __launch_bounds__(256)
void k_pre(const float* __restrict__ target,
           const float* __restrict__ t_g, const float* __restrict__ t_b,
           float* __restrict__ th, unsigned short* __restrict__ gcat,
           const float* __restrict__ sw1, const float* __restrict__ gw1,
           unsigned short* __restrict__ WtA, unsigned short* __restrict__ WtB,
           unsigned short* __restrict__ WtG,
           float* __restrict__ scores, const float* __restrict__ sb2,
           float* __restrict__ gacc, const float* __restrict__ gb2,
           const unsigned char* __restrict__ m, int* __restrict__ flag){
  int blk = blockIdx.x;
  int t = threadIdx.x;
  if (blk < 128){
    int i = blk * 256 + t;
    if (i < 32768) scores[i] = sb2[0];
    if (i < 4096)  gacc[i]   = gb2[0];
    if (blk == 0){
      __shared__ int s;
      if (t == 0) s = 0;
      __syncthreads();
      int nz = 0;
      for (int j = t; j < 2048; j += 256) nz += (m[4*j+1] != 0);
      atomicAdd(&s, nz);
      __syncthreads();
      if (t == 0) *flag = (s == 0) ? 1 : 0; // 1 => 4-byte mask elems
    }
    return;
  }
  if (blk < 2456){
    int tile = blk - 128;
    const float* W; unsigned short* Wt; int Kin, Kpad;
    if (tile < 576)      { W = sw1;              Wt = WtA; Kin = 768;  Kpad = 768;  }
    else if (tile < 1152){ W = sw1 + 768ull*768; Wt = WtB; Kin = 768;  Kpad = 768;  tile -= 576; }
    else                 { W = gw1;              Wt = WtG; Kin = 1552; Kpad = 1568; tile -= 1152; }
    int ntk = Kpad >> 5;
    int k0 = (tile % ntk) << 5, n0 = (tile / ntk) << 5;
    __shared__ float ts[32][33];
    int tx = t & 31, ty = t >> 5; // 32x8
    #pragma unroll
    for (int r = 0; r < 4; ++r){
      int k = k0 + ty + r*8;
      ts[ty + r*8][tx] = (k < Kin) ? W[(size_t)k * D768 + n0 + tx] : 0.f;
    }
    __syncthreads();
    #pragma unroll
    for (int r = 0; r < 4; ++r){
      int n = n0 + ty + r*8;
      Wt[(size_t)n * Kpad + k0 + tx] = f2bf(ts[tx][ty + r*8]);
    }
    return;
  }
  // target LayerNorm: 1 wave per row, 4 rows per block
  int row = (blk - 2456) * 4 + (t >> 6);
  int lane = t & 63;
  const float* xr = target + (size_t)row * D768;
  float4 v0 = *(const float4*)(xr + lane*4);
  float4 v1 = *(const float4*)(xr + 256 + lane*4);
  float4 v2 = *(const float4*)(xr + 512 + lane*4);
  float s  = v0.x+v0.y+v0.z+v0.w + v1.x+v1.y+v1.z+v1.w + v2.x+v2.y+v2.z+v2.w;
  float ss = v0.x*v0.x+v0.y*v0.y+v0.z*v0.z+v0.w*v0.w
           + v1.x*v1.x+v1.y*v1.y+v1.z*v1.z+v1.w*v1.w
           + v2.x*v2.x+v2.y*v2.y+v2.z*v2.z+v2.w*v2.w;
  #pragma unroll
  for (int o = 32; o; o >>= 1){ s += __shfl_xor(s, o); ss += __shfl_xor(ss, o); }
  float mean = s * (1.f/768.f);
  float var  = ss * (1.f/768.f) - mean*mean;
  float rstd = rsqrtf(var + 1e-5f);
  #pragma unroll
  for (int k = 0; k < 3; ++k){
    int c = lane*4 + k*256;
    float4 v = (k==0) ? v0 : (k==1) ? v1 : v2;
    float4 gv = *(const float4*)(t_g + c);
    float4 bv = *(const float4*)(t_b + c);
    float o0 = (v.x-mean)*rstd*gv.x + bv.x;
    float o1 = (v.y-mean)*rstd*gv.y + bv.y;
    float o2 = (v.z-mean)*rstd*gv.z + bv.z;
    float o3 = (v.w-mean)*rstd*gv.w + bv.w;
    float4 ov; ov.x=o0; ov.y=o1; ov.z=o2; ov.w=o3;
    *(float4*)(th + (size_t)row * D768 + c) = ov;
    ushort4 ub; ub.x=f2bf(o0); ub.y=f2bf(o1); ub.z=f2bf(o2); ub.w=f2bf(o3);
    *(ushort4*)(gcat + (size_t)row * 1568 + c) = ub;
  }
}

// ---------- OVERLAP kernel: tproj GEMM (blocks 0..383) + support LN (384..8575) ----------
// tproj (latency-bound, 4-wave 128x64 depth-3 ring) co-scheduled with the BW-bound
// support LN so its latency hides under the LN's HBM streaming.
__global__ __launch_bounds__(256)
void k_slntp(const float* __restrict__ support,
             const float* __restrict__ s_g, const float* __restrict__ s_b,
             unsigned short* __restrict__ sh,
             const unsigned short* __restrict__ gcat,   // A (th bf16), lda=1568
             const unsigned short* __restrict__ WtA,    // B^T, ldb=768
             float* __restrict__ tproj){
  __shared__ __align__(16) unsigned short As[3][128*32];
  __shared__ __align__(16) unsigned short Bs[3][64*32];
  int blk = blockIdx.x;
  int t = threadIdx.x;
  if (blk < 384){
    // --- tproj GEMM: 128x64 tile, ntn=12, ksteps=24, depth-3 one-barrier ring ---
    const int logical = (blk & 7) * 48 + (blk >> 3);  // XCD swizzle over 384 (384%8==0)
    const int m0 = (logical / 12) * 128, n0 = (logical % 12) * 64;
    const int lane = t & 63, w = t >> 6;
    const int wrow = (w >> 1) * 64, wcol = (w & 1) * 32;
    const int lo16 = lane & 15;
    const int hs = ((lane >> 4) ^ ((lo16 >> 1) & 3)) * 8;
    const int crow = lane >> 2;
    const int cseg = (((lane & 3) ^ ((lane >> 3) & 3)) * 8);
    const unsigned short* ga = gcat + (size_t)(m0 + w*32 + crow) * 1568 + cseg;
    const unsigned short* gb = WtA  + (size_t)(n0 + w*16 + crow) * 768 + cseg;
    f32x4 acc[4][2] = {};

#define STAGEK(BUF, KS) do {                                                   \
    const unsigned short* gak_ = ga + (size_t)(KS)*32;                         \
    gload16(gak_,                  &As[BUF][w*1024]);                          \
    gload16(gak_ + (size_t)16*1568,&As[BUF][w*1024 + 512]);                    \
    if (w < 4) gload16(gb + (size_t)(KS)*32 + 0, &Bs[BUF][w*512]);             \
  } while (0)

#define COMPUTEK(BUF) do {                                                     \
    const unsigned short* pa_ = &As[BUF][(wrow + lo16)*32 + hs];               \
    const unsigned short* pb_ = &Bs[BUF][(wcol + lo16)*32 + hs];               \
    short8 af_[4], bf_[2];                                                     \
    _Pragma("unroll")                                                          \
    for (int i = 0; i < 4; ++i) af_[i] = *(const short8*)(pa_ + i*16*32);      \
    _Pragma("unroll")                                                          \
    for (int j = 0; j < 2; ++j) bf_[j] = *(const short8*)(pb_ + j*16*32);      \
    __builtin_amdgcn_s_setprio(1);                                             \
    _Pragma("unroll")                                                          \
    for (int i = 0; i < 4; ++i)                                                \
      _Pragma("unroll")                                                        \
      for (int j = 0; j < 2; ++j)                                              \
        acc[i][j] = __builtin_amdgcn_mfma_f32_16x16x32_bf16(af_[i], bf_[j], acc[i][j], 0, 0, 0); \
    __builtin_amdgcn_s_setprio(0);                                             \
  } while (0)

#define WAITN(n) asm volatile("s_waitcnt vmcnt(" #n ")" ::: "memory")

    STAGEK(0, 0);
    STAGEK(1, 1);
    for (int ks = 0; ks < 24; ++ks){
      int rem = 24 - ks;
      if (rem >= 2){ if (w < 4) WAITN(3); else WAITN(2); }
      else WAITN(0);
      __builtin_amdgcn_s_barrier();
      __builtin_amdgcn_sched_barrier(0);
      if (ks + 2 < 24) STAGEK((ks + 2) % 3, ks + 2);
      COMPUTEK(ks % 3);
    }
#undef STAGEK
#undef COMPUTEK
#undef WAITN

    // wave rows [wrow,wrow+64), cols [wcol, wcol+32)
    #pragma unroll
    for (int i = 0; i < 4; ++i)
      #pragma unroll
      for (int reg = 0; reg < 4; ++reg){
        int row = m0 + wrow + i*16 + ((lane >> 4) << 2) + reg;
        float* orow = tproj + (size_t)row * D768 + n0 + wcol + lo16;
        #pragma unroll
        for (int j = 0; j < 2; ++j) orow[j*16] = acc[i][j][reg];
      }
    return;
  }
  // --- support LayerNorm: 1 wave per row, 4 rows per block ---
  int row = (blk - 384) * 4 + (t >> 6);
  int lane = t & 63;
  const float* xr = support + (size_t)row * D768;
  float4 v0 = *(const float4*)(xr + lane*4);
  float4 v1 = *(const float4*)(xr + 256 + lane*4);
  float4 v2 = *(const float4*)(xr + 512 + lane*4);
  float s  = v0.x+v0.y+v0.z+v0.w + v1.x+v1.y+v1.z+v1.w + v2.x+v2.y+v2.z+v2.w;
  float ss = v0.x*v0.x+v0.y*v0.y+v0.z*v0.z+v0.w*v0.w
           + v1.x*v1.x+v1.y*v1.y+v1.z*v1.z+v1.w*v1.w
           + v2.x*v2.x+v2.y*v2.y+v2.z*v2.z+v2.w*v2.w;
  #pragma unroll
  for (int o = 32; o; o >>= 1){ s += __shfl_xor(s, o); ss += __shfl_xor(ss, o); }
  float mean = s * (1.f/768.f);
  float var  = ss * (1.f/768.f) - mean*mean;
  float rstd = rsqrtf(var + 1e-5f);
  #pragma unroll
  for (int k = 0; k < 3; ++k){
    int c = lane*4 + k*256;
    float4 v = (k==0) ? v0 : (k==1) ? v1 : v2;
    float4 gv = *(const float4*)(s_g + c);
    float4 bv = *(const float4*)(s_b + c);
    float o0 = (v.x-mean)*rstd*gv.x + bv.x;
    float o1 = (v.y-mean)*rstd*gv.y + bv.y;
    float o2 = (v.z-mean)*rstd*gv.z + bv.z;
    float o3 = (v.w-mean)*rstd*gv.w + bv.w;
    ushort4 ub; ub.x=f2bf(o0); ub.y=f2bf(o1); ub.z=f2bf(o2); ub.w=f2bf(o3);
    *(ushort4*)(sh + (size_t)row * D768 + c) = ub;
  }
}

// ---------- 8-wave MFMA GEMM (score), 256x128 tile, depth-3 ring ----------
// Best measured score-GEMM configuration (R16: 71.3us).
__launch_bounds__(512)
__global__ void k_gemm8(const unsigned short* __restrict__ A, int lda,
                        const unsigned short* __restrict__ Bt, int ldb,
                        int ksteps, int ntn,
                        const float* __restrict__ tproj,
                        const float* __restrict__ b1,
                        const float* __restrict__ w2,
                        float* __restrict__ out){
  __shared__ __align__(16) unsigned short As[3][256*32];
  __shared__ __align__(16) unsigned short Bs[3][128*32];
  const int cpx = gridDim.x >> 3;
  const int logical = ((int)blockIdx.x & 7) * cpx + ((int)blockIdx.x >> 3);
  const int m0 = (logical / ntn) * 256, n0 = (logical % ntn) * 128;
  const int t = threadIdx.x, lane = t & 63, w = t >> 6; // 8 waves, 4M x 2N
  const int wrow = (w >> 1) * 64, wcol = (w & 1) * 64;
  const int lo16 = lane & 15;
  const int hs = ((lane >> 4) ^ ((lo16 >> 1) & 3)) * 8;
  const int crow = lane >> 2;
  const int cseg = (((lane & 3) ^ ((lane >> 3) & 3)) * 8);
  const unsigned short* ga = A  + (size_t)(m0 + w*32 + crow) * lda + cseg;
  const unsigned short* gb = Bt + (size_t)(n0 + w*16 + crow) * ldb + cseg;
  f32x4 acc[4][4] = {};

#define STAGEK(BUF, KS) do {                                                   \
    const unsigned short* gak_ = ga + (size_t)(KS)*32;                         \
    gload16(gak_,                    &As[BUF][w*1024]);                        \
    gload16(gak_ + (size_t)16*lda,   &As[BUF][w*1024 + 512]);                  \
    gload16(gb + (size_t)(KS)*32,    &Bs[BUF][w*512]);                         \
  } while (0)

#define COMPUTEK(BUF) do {                                                     \
    const unsigned short* pa_ = &As[BUF][(wrow + lo16)*32 + hs];               \
    const unsigned short* pb_ = &Bs[BUF][(wcol + lo16)*32 + hs];               \
    short8 af_[4], bf_[4];                                                     \
    _Pragma("unroll")                                                          \
    for (int i = 0; i < 4; ++i) af_[i] = *(const short8*)(pa_ + i*16*32);      \
    _Pragma("unroll")                                                          \
    for (int j = 0; j < 4; ++j) bf_[j] = *(const short8*)(pb_ + j*16*32);      \
    __builtin_amdgcn_s_setprio(1);                                             \
    _Pragma("unroll")                                                          \
    for (int i = 0; i < 4; ++i)                                                \
      _Pragma("unroll")                                                        \
      for (int j = 0; j < 4; ++j)                                              \
        acc[i][j] = __builtin_amdgcn_mfma_f32_16x16x32_bf16(af_[i], bf_[j], acc[i][j], 0, 0, 0); \
    __builtin_amdgcn_s_setprio(0);                                             \
  } while (0)

#define WAITN(n) asm volatile("s_waitcnt vmcnt(" #n ")" ::: "memory")

  {
    int pro = ksteps < 2 ? ksteps : 2;
    for (int p = 0; p < pro; ++p) STAGEK(p, p);
  }
  for (int ks = 0; ks < ksteps; ++ks){
    int rem = ksteps - ks;
    if (rem >= 2) WAITN(3);
    else WAITN(0);
    __builtin_amdgcn_s_barrier();
    __builtin_amdgcn_sched_barrier(0);
    if (ks + 2 < ksteps) STAGEK((ks + 2) % 3, ks + 2);
    COMPUTEK(ks % 3);
  }
#undef STAGEK
#undef COMPUTEK
#undef WAITN

  // epilogue: hoist b1/w2 (4 cols per thread), then per-row tproj + gelu + reduce
  float b1v[4], w2v[4];
  #pragma unroll
  for (int j = 0; j < 4; ++j){
    int n = n0 + wcol + j*16 + lo16;
    b1v[j] = b1[n]; w2v[j] = w2[n];
  }
  #pragma unroll
  for (int i = 0; i < 4; ++i)
    #pragma unroll
    for (int reg = 0; reg < 4; ++reg){
      int row = m0 + wrow + i*16 + ((lane >> 4) << 2) + reg;
      int trow = ((row >> 13) << 10) | (row & 1023);
      const float* tp = tproj + (size_t)trow * D768;
      float contrib = 0.f;
      #pragma unroll
      for (int j = 0; j < 4; ++j){
        int n = n0 + wcol + j*16 + lo16;
        float v = acc[i][j][reg] + b1v[j] + tp[n];
        contrib += gelu_f(v) * w2v[j];
      }
      for (int o = 8; o; o >>= 1) contrib += __shfl_xor(contrib, o);
      if (lo16 == 0) atomicAdd(&out[row], contrib);
    }
}

// ---------- 8-wave MFMA GEMM (gate), 128x64 tile, depth-3 ring ----------
__launch_bounds__(512)
__global__ void k_gemm8g(const unsigned short* __restrict__ A, int lda,
                         const unsigned short* __restrict__ Bt, int ldb,
                         int ksteps, int ntn,
                         const float* __restrict__ b1,
                         const float* __restrict__ w2,
                         float* __restrict__ out){
  __shared__ __align__(16) unsigned short As[3][128*32];
  __shared__ __align__(16) unsigned short Bs[3][64*32];
  const int cpx = gridDim.x >> 3;
  const int logical = ((int)blockIdx.x & 7) * cpx + ((int)blockIdx.x >> 3);
  const int m0 = (logical / ntn) * 128, n0 = (logical % ntn) * 64;
  const int t = threadIdx.x, lane = t & 63, w = t >> 6; // 8 waves
  const int wrow = (w >> 2) * 64, wcol = (w & 3) * 16;
  const int lo16 = lane & 15;
  const int hs = ((lane >> 4) ^ ((lo16 >> 1) & 3)) * 8;
  const int crow = lane >> 2;
  const int cseg = (((lane & 3) ^ ((lane >> 3) & 3)) * 8);
  const unsigned short* ga = A  + (size_t)(m0 + w*16 + crow) * lda + cseg;
  const unsigned short* gb = Bt + (size_t)(n0 + w*16 + crow) * ldb + cseg; // valid for w<4
  f32x4 acc[4] = {};

#define STAGEK(BUF, KS) do {                                                   \
    gload16(ga + (size_t)(KS)*32, &As[BUF][w*512]);                            \
    if (w < 4) gload16(gb + (size_t)(KS)*32, &Bs[BUF][w*512]);                 \
  } while (0)

#define COMPUTEK(BUF) do {                                                     \
    const unsigned short* pa_ = &As[BUF][(wrow + lo16)*32 + hs];               \
    const unsigned short* pb_ = &Bs[BUF][(wcol + lo16)*32 + hs];               \
    short8 af_[4], bf_;                                                        \
    _Pragma("unroll")                                                          \
    for (int i = 0; i < 4; ++i) af_[i] = *(const short8*)(pa_ + i*16*32);      \
    bf_ = *(const short8*)pb_;                                                 \
    __builtin_amdgcn_s_setprio(1);                                             \
    _Pragma("unroll")                                                          \
    for (int i = 0; i < 4; ++i)                                                \
      acc[i] = __builtin_amdgcn_mfma_f32_16x16x32_bf16(af_[i], bf_, acc[i], 0, 0, 0); \
    __builtin_amdgcn_s_setprio(0);                                             \
  } while (0)

#define WAITN(n) asm volatile("s_waitcnt vmcnt(" #n ")" ::: "memory")

  {
    int pro = ksteps < 2 ? ksteps : 2;
    for (int p = 0; p < pro; ++p) STAGEK(p, p);
  }
  for (int ks = 0; ks < ksteps; ++ks){
    int rem = ksteps - ks;
    if (rem >= 2){ if (w < 4) WAITN(2); else WAITN(1); }
    else WAITN(0);
    __builtin_amdgcn_s_barrier();
    __builtin_amdgcn_sched_barrier(0);
    if (ks + 2 < ksteps) STAGEK((ks + 2) % 3, ks + 2);
    COMPUTEK(ks % 3);
  }
#undef STAGEK
#undef COMPUTEK
#undef WAITN

  #pragma unroll
  for (int i = 0; i < 4; ++i)
    #pragma unroll
    for (int reg = 0; reg < 4; ++reg){
      int row = m0 + wrow + i*16 + ((lane >> 4) << 2) + reg;
      int n = n0 + wcol + lo16;
      float v = acc[i][reg] + b1[n];
      float contrib = gelu_f(v) * w2[n];
      for (int o = 8; o; o >>= 1) contrib += __shfl_xor(contrib, o);
      if (lo16 == 0) atomicAdd(&out[row], contrib);
    }
}

// ---------- masked softmax over S=8 + weighted summary -> gcat[:,768:1568] (bf16) ----------
__global__ void k_smx(const float* __restrict__ scores, const void* __restrict__ maskp,
                      const int* __restrict__ flag, const unsigned short* __restrict__ sh,
                      const float* __restrict__ feat,
                      unsigned short* __restrict__ gcat){
  int bt = blockIdx.x;
  int b = bt >> 10, tt = bt & 1023;
  int t = threadIdx.x; // 192
  int f = *flag;
  float sc[8], mk[8];
  #pragma unroll
  for (int s = 0; s < 8; ++s){
    size_t idx = ((size_t)(b*8 + s) << 10) + tt;
    bool m = f ? (((const int*)maskp)[idx] != 0)
               : (((const unsigned char*)maskp)[idx] != 0);
    mk[s] = m ? 1.f : 0.f;
    float v = scores[idx];
    sc[s] = m ? v : -10000.f;
  }
  float mx = sc[0];
  #pragma unroll
  for (int s = 1; s < 8; ++s) mx = fmaxf(mx, sc[s]);
  float e[8], sum = 0.f;
  #pragma unroll
  for (int s = 0; s < 8; ++s){ e[s] = __expf(sc[s] - mx); sum += e[s]; }
  float inv = 1.f / sum;
  float wv[8], sum2 = 0.f;
  #pragma unroll
  for (int s = 0; s < 8; ++s){ wv[s] = e[s] * inv * mk[s]; sum2 += wv[s]; }
  float inv2 = 1.f / fmaxf(sum2, 1e-8f);
  #pragma unroll
  for (int s = 0; s < 8; ++s) wv[s] *= inv2;
  float a0=0.f, a1=0.f, a2=0.f, a3=0.f;
  #pragma unroll
  for (int s = 0; s < 8; ++s){
    const unsigned short* p = sh + (((size_t)(b*8+s) << 10) + tt) * D768 + t*4;
    ushort4 u = *(const ushort4*)p;
    float ws = wv[s];
    a0 += ws * bf2f(u.x); a1 += ws * bf2f(u.y); a2 += ws * bf2f(u.z); a3 += ws * bf2f(u.w);
  }
  ushort4 ub; ub.x=f2bf(a0); ub.y=f2bf(a1); ub.z=f2bf(a2); ub.w=f2bf(a3);
  *(ushort4*)(gcat + (size_t)bt * 1568 + 768 + t*4) = ub;
  if (t < 8){
    int c = 1536 + t*4;
    float4 fv = make_float4(0.f, 0.f, 0.f, 0.f);
    if (c < 1552) fv = *(const float4*)(feat + (size_t)bt * 16 + (c - 1536));
    ushort4 uf; uf.x=f2bf(fv.x); uf.y=f2bf(fv.y); uf.z=f2bf(fv.z); uf.w=f2bf(fv.w);
    *(ushort4*)(gcat + (size_t)bt * 1568 + c) = uf;
  }
}

// ---------- gate=sigmoid(gacc); x=(2-g)*th+g*summary; out=LN(x). 1 wave/row ----------
__global__ __launch_bounds__(256)
void k_final(const float* __restrict__ th, const unsigned short* __restrict__ gcat,
             const float* __restrict__ gacc, const float* __restrict__ og,
             const float* __restrict__ ob, float* __restrict__ out,
             float* __restrict__ outg){
  int row = blockIdx.x * 4 + (threadIdx.x >> 6);
  int lane = threadIdx.x & 63;
  float gv = 1.f / (1.f + __expf(-gacc[row]));
  if (lane == 0) outg[row] = gv;
  const float* tr = th + (size_t)row * D768;
  const unsigned short* sr = gcat + (size_t)row * 1568 + 768;
  float x[12];
  float s = 0.f, ss = 0.f;
  #pragma unroll
  for (int k = 0; k < 3; ++k){
    int c = lane*4 + k*256;
    float4 tv = *(const float4*)(tr + c);
    ushort4 su = *(const ushort4*)(sr + c);
    float v0 = (2.f-gv)*tv.x + gv*bf2f(su.x);
    float v1 = (2.f-gv)*tv.y + gv*bf2f(su.y);
    float v2 = (2.f-gv)*tv.z + gv*bf2f(su.z);
    float v3 = (2.f-gv)*tv.w + gv*bf2f(su.w);
    x[k*4+0]=v0; x[k*4+1]=v1; x[k*4+2]=v2; x[k*4+3]=v3;
    s += v0+v1+v2+v3;
    ss += v0*v0+v1*v1+v2*v2+v3*v3;
  }
  #pragma unroll
  for (int o = 32; o; o >>= 1){ s += __shfl_xor(s, o); ss += __shfl_xor(ss, o); }
  float mean = s*(1.f/768.f), var = ss*(1.f/768.f)-mean*mean;
  float rstd = rsqrtf(var + 1e-5f);
  #pragma unroll
  for (int k = 0; k < 3; ++k){
    int c = lane*4 + k*256;
    float4 gvv = *(const float4*)(og + c);
    float4 bvv = *(const float4*)(ob + c);
    float4 ov;
    ov.x = (x[k*4+0]-mean)*rstd*gvv.x + bvv.x;
    ov.y = (x[k*4+1]-mean)*rstd*gvv.y + bvv.y;
    ov.z = (x[k*4+2]-mean)*rstd*gvv.z + bvv.z;
    ov.w = (x[k*4+3]-mean)*rstd*gvv.w + bvv.w;
    *(float4*)(out + (size_t)row * D768 + c) = ov;
  }
}

extern "C" void kernel_launch(void* const* d_in, const int* in_sizes, int n_in,
                              void* d_out, int out_size, void* d_ws, size_t ws_size,
                              hipStream_t stream){
  const float* target = (const float*)d_in[0];
  const float* support= (const float*)d_in[1];
  const void*  maskp  = d_in[2];
  const float* feat   = (const float*)d_in[3];
  const float* t_g = (const float*)d_in[4];
  const float* t_b = (const float*)d_in[5];
  const float* s_g = (const float*)d_in[6];
  const float* s_b = (const float*)d_in[7];
  const float* o_g = (const float*)d_in[8];
  const float* o_b = (const float*)d_in[9];
  const float* sw1 = (const float*)d_in[10];
  const float* sb1 = (const float*)d_in[11];
  const float* sw2 = (const float*)d_in[12];
  const float* sb2 = (const float*)d_in[13];
  const float* gw1 = (const float*)d_in[14];
  const float* gb1 = (const float*)d_in[15];
  const float* gw2 = (const float*)d_in[16];
  const float* gb2 = (const float*)d_in[17];

  char* wsb = (char*)d_ws;
  size_t off = 0;
  auto alloc = [&](size_t bytes)->void*{
    void* p = wsb + off; off += (bytes + 255) & ~(size_t)255; return p;
  };
  float* th            = (float*)alloc(4096ull*768*4);
  unsigned short* sh   = (unsigned short*)alloc(32768ull*768*2);
  float* tproj         = (float*)alloc(4096ull*768*4);
  unsigned short* gcat = (unsigned short*)alloc(4096ull*1568*2);
  unsigned short* WtA  = (unsigned short*)alloc(768ull*768*2);
  unsigned short* WtB  = (unsigned short*)alloc(768ull*768*2);
  unsigned short* WtG  = (unsigned short*)alloc(768ull*1568*2);
  float* scores        = (float*)alloc(32768ull*4);
  float* gacc          = (float*)alloc(4096ull*4);
  int*   flag          = (int*)alloc(256);

  float* outm = (float*)d_out;       // (B,T,D)
  float* outg = outm + 4096ull*768;  // (B,T)

  // init + maskdet + weight transposes + target LN
  k_pre<<<3480, 256, 0, stream>>>(target, t_g, t_b, th, gcat,
                                  sw1, gw1, WtA, WtB, WtG,
                                  scores, sb2, gacc, gb2,
                                  (const unsigned char*)maskp, flag);
  // support LN (BW-bound) overlapped with tproj GEMM (latency-bound)
  k_slntp<<<8576, 256, 0, stream>>>(support, s_g, s_b, sh, gcat, WtA, tproj);
  // scores += rowsum(gelu(sh@W1b + tproj + b1) * w2)   (256x128 tile, 768 blocks, ntn=6)
  k_gemm8<<<768, 512, 0, stream>>>(sh, 768, WtB, 768, 24, 6,
                                   tproj, sb1, sw2, scores);
  // masked softmax + summary -> gcat[:, 768:1568]
  k_smx<<<4096, 192, 0, stream>>>(scores, maskp, flag, sh, feat, gcat);
  // gate_acc += rowsum(gelu(gcat@gW1 + gb1) * gw2)   (8-wave, 384 blocks, ntn=12)
  k_gemm8g<<<384, 512, 0, stream>>>(gcat, 1568, WtG, 1568, 49, 12,
                                    gb1, gw2, gacc);
  k_final<<<1024, 256, 0, stream>>>(th, gcat, gacc, o_g, o_b, outm, outg);
}

// Round 20
// 157.402 us; speedup vs baseline: 1.2852x; 1.0221x over previous
//
#include <hip/hip_runtime.h>
#include <hip/hip_bf16.h>

#define D768 768

typedef __attribute__((ext_vector_type(8))) short short8;
typedef __attribute__((ext_vector_type(4))) float f32x4;

__device__ __forceinline__ unsigned short f2bf(float f){
  union { float f; unsigned u; } v; v.f = f;
  unsigned r = v.u + 0x7FFFu + ((v.u >> 16) & 1u);
  return (unsigned short)(r >> 16);
}
__device__ __forceinline__ float bf2f(unsigned short u){
  union { unsigned u; float f; } v; v.u = ((unsigned)u) << 16;
  return v.f;
}
// exact-erf GELU via Abramowitz-Stegun 7.1.26 (|eps| <= 1.5e-7), ~13 VALU + exp + rcp
__device__ __forceinline__ float gelu_f(float x){
  float y = fabsf(x) * 0.7071067811865475f;
  float t = __builtin_amdgcn_rcpf(fmaf(0.3275911f, y, 1.0f));
  float p = fmaf(fmaf(fmaf(fmaf(1.061405429f, t, -1.453152027f), t, 1.421413741f),
                      t, -0.284496736f), t, 0.254829592f) * t;
  float e = __expf(-y * y);
  float erf_abs = fmaf(-p, e, 1.0f);
  float erfv = copysignf(erf_abs, x);
  return 0.5f * x * (1.0f + erfv);
}
__device__ __forceinline__ void gload16(const void* g, void* l){
  __builtin_amdgcn_global_load_lds((const __attribute__((address_space(1))) void*)g,
                                   (__attribute__((address_space(3))) void*)l, 16, 0, 0);
}

// ---------- PRE kernel: init (0..127) + weight transpose (128..2455) +
// target LN (2456..3479, 4 rows/block, 1 wave/row) ----------
__global__ __launch_bounds__(256)
void k_pre(const float* __restrict__ target,
           const float* __restrict__ t_g, const float* __restrict__ t_b,
           float* __restrict__ th, unsigned short* __restrict__ gcat,
           const float* __restrict__ sw1, const float* __restrict__ gw1,
           unsigned short* __restrict__ WtA, unsigned short* __restrict__ WtB,
           unsigned short* __restrict__ WtG,
           float* __restrict__ scores, const float* __restrict__ sb2,
           float* __restrict__ gacc, const float* __restrict__ gb2,
           const unsigned char* __restrict__ m, int* __restrict__ flag){
  int blk = blockIdx.x;
  int t = threadIdx.x;
  if (blk < 128){
    int i = blk * 256 + t;
    if (i < 32768) scores[i] = sb2[0];
    if (i < 4096)  gacc[i]   = gb2[0];
    if (blk == 0){
      __shared__ int s;
      if (t == 0) s = 0;
      __syncthreads();
      int nz = 0;
      for (int j = t; j < 2048; j += 256) nz += (m[4*j+1] != 0);
      atomicAdd(&s, nz);
      __syncthreads();
      if (t == 0) *flag = (s == 0) ? 1 : 0; // 1 => 4-byte mask elems
    }
    return;
  }
  if (blk < 2456){
    int tile = blk - 128;
    const float* W; unsigned short* Wt; int Kin, Kpad;
    if (tile < 576)      { W = sw1;              Wt = WtA; Kin = 768;  Kpad = 768;  }
    else if (tile < 1152){ W = sw1 + 768ull*768; Wt = WtB; Kin = 768;  Kpad = 768;  tile -= 576; }
    else                 { W = gw1;              Wt = WtG; Kin = 1552; Kpad = 1568; tile -= 1152; }
    int ntk = Kpad >> 5;
    int k0 = (tile % ntk) << 5, n0 = (tile / ntk) << 5;
    __shared__ float ts[32][33];
    int tx = t & 31, ty = t >> 5; // 32x8
    #pragma unroll
    for (int r = 0; r < 4; ++r){
      int k = k0 + ty + r*8;
      ts[ty + r*8][tx] = (k < Kin) ? W[(size_t)k * D768 + n0 + tx] : 0.f;
    }
    __syncthreads();
    #pragma unroll
    for (int r = 0; r < 4; ++r){
      int n = n0 + ty + r*8;
      Wt[(size_t)n * Kpad + k0 + tx] = f2bf(ts[tx][ty + r*8]);
    }
    return;
  }
  // target LayerNorm: 1 wave per row, 4 rows per block
  int row = (blk - 2456) * 4 + (t >> 6);
  int lane = t & 63;
  const float* xr = target + (size_t)row * D768;
  float4 v0 = *(const float4*)(xr + lane*4);
  float4 v1 = *(const float4*)(xr + 256 + lane*4);
  float4 v2 = *(const float4*)(xr + 512 + lane*4);
  float s  = v0.x+v0.y+v0.z+v0.w + v1.x+v1.y+v1.z+v1.w + v2.x+v2.y+v2.z+v2.w;
  float ss = v0.x*v0.x+v0.y*v0.y+v0.z*v0.z+v0.w*v0.w
           + v1.x*v1.x+v1.y*v1.y+v1.z*v1.z+v1.w*v1.w
           + v2.x*v2.x+v2.y*v2.y+v2.z*v2.z+v2.w*v2.w;
  #pragma unroll
  for (int o = 32; o; o >>= 1){ s += __shfl_xor(s, o); ss += __shfl_xor(ss, o); }
  float mean = s * (1.f/768.f);
  float var  = ss * (1.f/768.f) - mean*mean;
  float rstd = rsqrtf(var + 1e-5f);
  #pragma unroll
  for (int k = 0; k < 3; ++k){
    int c = lane*4 + k*256;
    float4 v = (k==0) ? v0 : (k==1) ? v1 : v2;
    float4 gv = *(const float4*)(t_g + c);
    float4 bv = *(const float4*)(t_b + c);
    float o0 = (v.x-mean)*rstd*gv.x + bv.x;
    float o1 = (v.y-mean)*rstd*gv.y + bv.y;
    float o2 = (v.z-mean)*rstd*gv.z + bv.z;
    float o3 = (v.w-mean)*rstd*gv.w + bv.w;
    float4 ov; ov.x=o0; ov.y=o1; ov.z=o2; ov.w=o3;
    *(float4*)(th + (size_t)row * D768 + c) = ov;
    ushort4 ub; ub.x=f2bf(o0); ub.y=f2bf(o1); ub.z=f2bf(o2); ub.w=f2bf(o3);
    *(ushort4*)(gcat + (size_t)row * 1568 + c) = ub;
  }
}

// ---------- OVERLAP kernel: tproj GEMM (blocks 0..383) + support LN (384..8575) ----------
__global__ __launch_bounds__(256)
void k_slntp(const float* __restrict__ support,
             const float* __restrict__ s_g, const float* __restrict__ s_b,
             unsigned short* __restrict__ sh,
             const unsigned short* __restrict__ gcat,   // A (th bf16), lda=1568
             const unsigned short* __restrict__ WtA,    // B^T, ldb=768
             float* __restrict__ tproj){
  __shared__ __align__(16) unsigned short As[3][128*32];
  __shared__ __align__(16) unsigned short Bs[3][64*32];
  int blk = blockIdx.x;
  int t = threadIdx.x;
  if (blk < 384){
    // --- tproj GEMM: 128x64 tile, ntn=12, ksteps=24, depth-3 one-barrier ring ---
    const int logical = (blk & 7) * 48 + (blk >> 3);  // XCD swizzle over 384
    const int m0 = (logical / 12) * 128, n0 = (logical % 12) * 64;
    const int lane = t & 63, w = t >> 6;
    const int wrow = (w >> 1) * 64, wcol = (w & 1) * 32;
    const int lo16 = lane & 15;
    const int hs = ((lane >> 4) ^ ((lo16 >> 1) & 3)) * 8;
    const int crow = lane >> 2;
    const int cseg = (((lane & 3) ^ ((lane >> 3) & 3)) * 8);
    const unsigned short* ga = gcat + (size_t)(m0 + w*32 + crow) * 1568 + cseg;
    const unsigned short* gb = WtA  + (size_t)(n0 + w*16 + crow) * 768 + cseg;
    f32x4 acc[4][2] = {};

#define STAGEK(BUF, KS) do {                                                   \
    const unsigned short* gak_ = ga + (size_t)(KS)*32;                         \
    gload16(gak_,                  &As[BUF][w*1024]);                          \
    gload16(gak_ + (size_t)16*1568,&As[BUF][w*1024 + 512]);                    \
    if (w < 4) gload16(gb + (size_t)(KS)*32 + 0, &Bs[BUF][w*512]);             \
  } while (0)

#define COMPUTEK(BUF) do {                                                     \
    const unsigned short* pa_ = &As[BUF][(wrow + lo16)*32 + hs];               \
    const unsigned short* pb_ = &Bs[BUF][(wcol + lo16)*32 + hs];               \
    short8 af_[4], bf_[2];                                                     \
    _Pragma("unroll")                                                          \
    for (int i = 0; i < 4; ++i) af_[i] = *(const short8*)(pa_ + i*16*32);      \
    _Pragma("unroll")                                                          \
    for (int j = 0; j < 2; ++j) bf_[j] = *(const short8*)(pb_ + j*16*32);      \
    __builtin_amdgcn_s_setprio(1);                                             \
    _Pragma("unroll")                                                          \
    for (int i = 0; i < 4; ++i)                                                \
      _Pragma("unroll")                                                        \
      for (int j = 0; j < 2; ++j)                                              \
        acc[i][j] = __builtin_amdgcn_mfma_f32_16x16x32_bf16(af_[i], bf_[j], acc[i][j], 0, 0, 0); \
    __builtin_amdgcn_s_setprio(0);                                             \
  } while (0)

#define WAITN(n) asm volatile("s_waitcnt vmcnt(" #n ")" ::: "memory")

    STAGEK(0, 0);
    STAGEK(1, 1);
    for (int ks = 0; ks < 24; ++ks){
      int rem = 24 - ks;
      if (rem >= 2){ if (w < 4) WAITN(3); else WAITN(2); }
      else WAITN(0);
      __builtin_amdgcn_s_barrier();
      __builtin_amdgcn_sched_barrier(0);
      if (ks + 2 < 24) STAGEK((ks + 2) % 3, ks + 2);
      COMPUTEK(ks % 3);
    }
#undef STAGEK
#undef COMPUTEK
#undef WAITN

    #pragma unroll
    for (int i = 0; i < 4; ++i)
      #pragma unroll
      for (int reg = 0; reg < 4; ++reg){
        int row = m0 + wrow + i*16 + ((lane >> 4) << 2) + reg;
        float* orow = tproj + (size_t)row * D768 + n0 + wcol + lo16;
        #pragma unroll
        for (int j = 0; j < 2; ++j) orow[j*16] = acc[i][j][reg];
      }
    return;
  }
  // --- support LayerNorm: 1 wave per row, 4 rows per block ---
  int row = (blk - 384) * 4 + (t >> 6);
  int lane = t & 63;
  const float* xr = support + (size_t)row * D768;
  float4 v0 = *(const float4*)(xr + lane*4);
  float4 v1 = *(const float4*)(xr + 256 + lane*4);
  float4 v2 = *(const float4*)(xr + 512 + lane*4);
  float s  = v0.x+v0.y+v0.z+v0.w + v1.x+v1.y+v1.z+v1.w + v2.x+v2.y+v2.z+v2.w;
  float ss = v0.x*v0.x+v0.y*v0.y+v0.z*v0.z+v0.w*v0.w
           + v1.x*v1.x+v1.y*v1.y+v1.z*v1.z+v1.w*v1.w
           + v2.x*v2.x+v2.y*v2.y+v2.z*v2.z+v2.w*v2.w;
  #pragma unroll
  for (int o = 32; o; o >>= 1){ s += __shfl_xor(s, o); ss += __shfl_xor(ss, o); }
  float mean = s * (1.f/768.f);
  float var  = ss * (1.f/768.f) - mean*mean;
  float rstd = rsqrtf(var + 1e-5f);
  #pragma unroll
  for (int k = 0; k < 3; ++k){
    int c = lane*4 + k*256;
    float4 v = (k==0) ? v0 : (k==1) ? v1 : v2;
    float4 gv = *(const float4*)(s_g + c);
    float4 bv = *(const float4*)(s_b + c);
    float o0 = (v.x-mean)*rstd*gv.x + bv.x;
    float o1 = (v.y-mean)*rstd*gv.y + bv.y;
    float o2 = (v.z-mean)*rstd*gv.z + bv.z;
    float o3 = (v.w-mean)*rstd*gv.w + bv.w;
    ushort4 ub; ub.x=f2bf(o0); ub.y=f2bf(o1); ub.z=f2bf(o2); ub.w=f2bf(o3);
    *(ushort4*)(sh + (size_t)row * D768 + c) = ub;
  }
}

// ---------- 8-wave MFMA GEMM (score), 256x128 tile, depth-3 ring ----------
// Best measured score-GEMM configuration (R16: ~71.3us).
__launch_bounds__(512)
__global__ void k_gemm8(const unsigned short* __restrict__ A, int lda,
                        const unsigned short* __restrict__ Bt, int ldb,
                        int ksteps, int ntn,
                        const float* __restrict__ tproj,
                        const float* __restrict__ b1,
                        const float* __restrict__ w2,
                        float* __restrict__ out){
  __shared__ __align__(16) unsigned short As[3][256*32];
  __shared__ __align__(16) unsigned short Bs[3][128*32];
  const int cpx = gridDim.x >> 3;
  const int logical = ((int)blockIdx.x & 7) * cpx + ((int)blockIdx.x >> 3);
  const int m0 = (logical / ntn) * 256, n0 = (logical % ntn) * 128;
  const int t = threadIdx.x, lane = t & 63, w = t >> 6; // 8 waves, 4M x 2N
  const int wrow = (w >> 1) * 64, wcol = (w & 1) * 64;
  const int lo16 = lane & 15;
  const int hs = ((lane >> 4) ^ ((lo16 >> 1) & 3)) * 8;
  const int crow = lane >> 2;
  const int cseg = (((lane & 3) ^ ((lane >> 3) & 3)) * 8);
  const unsigned short* ga = A  + (size_t)(m0 + w*32 + crow) * lda + cseg;
  const unsigned short* gb = Bt + (size_t)(n0 + w*16 + crow) * ldb + cseg;
  f32x4 acc[4][4] = {};

#define STAGEK(BUF, KS) do {                                                   \
    const unsigned short* gak_ = ga + (size_t)(KS)*32;                         \
    gload16(gak_,                    &As[BUF][w*1024]);                        \
    gload16(gak_ + (size_t)16*lda,   &As[BUF][w*1024 + 512]);                  \
    gload16(gb + (size_t)(KS)*32,    &Bs[BUF][w*512]);                         \
  } while (0)

#define COMPUTEK(BUF) do {                                                     \
    const unsigned short* pa_ = &As[BUF][(wrow + lo16)*32 + hs];               \
    const unsigned short* pb_ = &Bs[BUF][(wcol + lo16)*32 + hs];               \
    short8 af_[4], bf_[4];                                                     \
    _Pragma("unroll")                                                          \
    for (int i = 0; i < 4; ++i) af_[i] = *(const short8*)(pa_ + i*16*32);      \
    _Pragma("unroll")                                                          \
    for (int j = 0; j < 4; ++j) bf_[j] = *(const short8*)(pb_ + j*16*32);      \
    __builtin_amdgcn_s_setprio(1);                                             \
    _Pragma("unroll")                                                          \
    for (int i = 0; i < 4; ++i)                                                \
      _Pragma("unroll")                                                        \
      for (int j = 0; j < 4; ++j)                                              \
        acc[i][j] = __builtin_amdgcn_mfma_f32_16x16x32_bf16(af_[i], bf_[j], acc[i][j], 0, 0, 0); \
    __builtin_amdgcn_s_setprio(0);                                             \
  } while (0)

#define WAITN(n) asm volatile("s_waitcnt vmcnt(" #n ")" ::: "memory")

  {
    int pro = ksteps < 2 ? ksteps : 2;
    for (int p = 0; p < pro; ++p) STAGEK(p, p);
  }
  for (int ks = 0; ks < ksteps; ++ks){
    int rem = ksteps - ks;
    if (rem >= 2) WAITN(3);
    else WAITN(0);
    __builtin_amdgcn_s_barrier();
    __builtin_amdgcn_sched_barrier(0);
    if (ks + 2 < ksteps) STAGEK((ks + 2) % 3, ks + 2);
    COMPUTEK(ks % 3);
  }
#undef STAGEK
#undef COMPUTEK
#undef WAITN

  // epilogue: hoist b1/w2 (4 cols per thread), then per-row tproj + gelu + reduce
  float b1v[4], w2v[4];
  #pragma unroll
  for (int j = 0; j < 4; ++j){
    int n = n0 + wcol + j*16 + lo16;
    b1v[j] = b1[n]; w2v[j] = w2[n];
  }
  #pragma unroll
  for (int i = 0; i < 4; ++i)
    #pragma unroll
    for (int reg = 0; reg < 4; ++reg){
      int row = m0 + wrow + i*16 + ((lane >> 4) << 2) + reg;
      int trow = ((row >> 13) << 10) | (row & 1023);
      const float* tp = tproj + (size_t)trow * D768;
      float contrib = 0.f;
      #pragma unroll
      for (int j = 0; j < 4; ++j){
        int n = n0 + wcol + j*16 + lo16;
        float v = acc[i][j][reg] + b1v[j] + tp[n];
        contrib += gelu_f(v) * w2v[j];
      }
      for (int o = 8; o; o >>= 1) contrib += __shfl_xor(contrib, o);
      if (lo16 == 0) atomicAdd(&out[row], contrib);
    }
}

// ---------- 8-wave MFMA GEMM (gate), 64x64 tile, depth-3 ring ----------
// 768 blocks (all co-resident at 24KB LDS, wave-capped 4 blocks/CU) vs 384 at
// 128x64 (1.5 blocks/CU grid-starved). Waves as 2M x 4N, each 32x16 (acc[2]).
// Staging: waves 0-3 one A-chunk (16 rows), waves 4-7 one B-chunk; 1 load/thread
// uniform -> steady vmcnt(1), tail vmcnt(0). Ring/barrier/swizzle as proven.
__launch_bounds__(512)
__global__ void k_gemm8g(const unsigned short* __restrict__ A, int lda,
                         const unsigned short* __restrict__ Bt, int ldb,
                         int ksteps, int ntn,
                         const float* __restrict__ b1,
                         const float* __restrict__ w2,
                         float* __restrict__ out){
  __shared__ __align__(16) unsigned short As[3][64*32];
  __shared__ __align__(16) unsigned short Bs[3][64*32];
  const int cpx = gridDim.x >> 3;
  const int logical = ((int)blockIdx.x & 7) * cpx + ((int)blockIdx.x >> 3);
  const int m0 = (logical / ntn) * 64, n0 = (logical % ntn) * 64;
  const int t = threadIdx.x, lane = t & 63, w = t >> 6; // 8 waves, 2M x 4N
  const int wrow = (w >> 2) * 32, wcol = (w & 3) * 16;
  const int lo16 = lane & 15;
  const int hs = ((lane >> 4) ^ ((lo16 >> 1) & 3)) * 8;
  const int crow = lane >> 2;
  const int cseg = (((lane & 3) ^ ((lane >> 3) & 3)) * 8);
  // waves 0-3 stage A rows [m0+w*16, +16); waves 4-7 stage B rows [n0+(w-4)*16, +16)
  const unsigned short* gs = (w < 4)
      ? (A  + (size_t)(m0 + w*16 + crow) * lda + cseg)
      : (Bt + (size_t)(n0 + (w-4)*16 + crow) * ldb + cseg);
  const size_t gstep = (w < 4) ? 0 : 0; (void)gstep;
  f32x4 acc[2] = {};

#define STAGEK(BUF, KS) do {                                                   \
    unsigned short* ld_ = (w < 4) ? &As[BUF][w*512] : &Bs[BUF][(w-4)*512];     \
    gload16(gs + (size_t)(KS)*32, ld_);                                        \
  } while (0)

#define COMPUTEK(BUF) do {                                                     \
    const unsigned short* pa_ = &As[BUF][(wrow + lo16)*32 + hs];               \
    const unsigned short* pb_ = &Bs[BUF][(wcol + lo16)*32 + hs];               \
    short8 af_[2], bf_;                                                        \
    _Pragma("unroll")                                                          \
    for (int i = 0; i < 2; ++i) af_[i] = *(const short8*)(pa_ + i*16*32);      \
    bf_ = *(const short8*)pb_;                                                 \
    __builtin_amdgcn_s_setprio(1);                                             \
    _Pragma("unroll")                                                          \
    for (int i = 0; i < 2; ++i)                                                \
      acc[i] = __builtin_amdgcn_mfma_f32_16x16x32_bf16(af_[i], bf_, acc[i], 0, 0, 0); \
    __builtin_amdgcn_s_setprio(0);                                             \
  } while (0)

#define WAITN(n) asm volatile("s_waitcnt vmcnt(" #n ")" ::: "memory")

  {
    int pro = ksteps < 2 ? ksteps : 2;
    for (int p = 0; p < pro; ++p) STAGEK(p, p);
  }
  for (int ks = 0; ks < ksteps; ++ks){
    int rem = ksteps - ks;
    if (rem >= 2) WAITN(1);
    else WAITN(0);
    __builtin_amdgcn_s_barrier();
    __builtin_amdgcn_sched_barrier(0);
    if (ks + 2 < ksteps) STAGEK((ks + 2) % 3, ks + 2);
    COMPUTEK(ks % 3);
  }
#undef STAGEK
#undef COMPUTEK
#undef WAITN

  // gate epilogue: +b1, gelu, *w2, 16-lane reduce, atomicAdd
  #pragma unroll
  for (int i = 0; i < 2; ++i)
    #pragma unroll
    for (int reg = 0; reg < 4; ++reg){
      int row = m0 + wrow + i*16 + ((lane >> 4) << 2) + reg;
      int n = n0 + wcol + lo16;
      float v = acc[i][reg] + b1[n];
      float contrib = gelu_f(v) * w2[n];
      for (int o = 8; o; o >>= 1) contrib += __shfl_xor(contrib, o);
      if (lo16 == 0) atomicAdd(&out[row], contrib);
    }
}

// ---------- masked softmax over S=8 + weighted summary -> gcat[:,768:1568] (bf16) ----------
__global__ void k_smx(const float* __restrict__ scores, const void* __restrict__ maskp,
                      const int* __restrict__ flag, const unsigned short* __restrict__ sh,
                      const float* __restrict__ feat,
                      unsigned short* __restrict__ gcat){
  int bt = blockIdx.x;
  int b = bt >> 10, tt = bt & 1023;
  int t = threadIdx.x; // 192
  int f = *flag;
  float sc[8], mk[8];
  #pragma unroll
  for (int s = 0; s < 8; ++s){
    size_t idx = ((size_t)(b*8 + s) << 10) + tt;
    bool m = f ? (((const int*)maskp)[idx] != 0)
               : (((const unsigned char*)maskp)[idx] != 0);
    mk[s] = m ? 1.f : 0.f;
    float v = scores[idx];
    sc[s] = m ? v : -10000.f;
  }
  float mx = sc[0];
  #pragma unroll
  for (int s = 1; s < 8; ++s) mx = fmaxf(mx, sc[s]);
  float e[8], sum = 0.f;
  #pragma unroll
  for (int s = 0; s < 8; ++s){ e[s] = __expf(sc[s] - mx); sum += e[s]; }
  float inv = 1.f / sum;
  float wv[8], sum2 = 0.f;
  #pragma unroll
  for (int s = 0; s < 8; ++s){ wv[s] = e[s] * inv * mk[s]; sum2 += wv[s]; }
  float inv2 = 1.f / fmaxf(sum2, 1e-8f);
  #pragma unroll
  for (int s = 0; s < 8; ++s) wv[s] *= inv2;
  float a0=0.f, a1=0.f, a2=0.f, a3=0.f;
  #pragma unroll
  for (int s = 0; s < 8; ++s){
    const unsigned short* p = sh + (((size_t)(b*8+s) << 10) + tt) * D768 + t*4;
    ushort4 u = *(const ushort4*)p;
    float ws = wv[s];
    a0 += ws * bf2f(u.x); a1 += ws * bf2f(u.y); a2 += ws * bf2f(u.z); a3 += ws * bf2f(u.w);
  }
  ushort4 ub; ub.x=f2bf(a0); ub.y=f2bf(a1); ub.z=f2bf(a2); ub.w=f2bf(a3);
  *(ushort4*)(gcat + (size_t)bt * 1568 + 768 + t*4) = ub;
  if (t < 8){
    int c = 1536 + t*4;
    float4 fv = make_float4(0.f, 0.f, 0.f, 0.f);
    if (c < 1552) fv = *(const float4*)(feat + (size_t)bt * 16 + (c - 1536));
    ushort4 uf; uf.x=f2bf(fv.x); uf.y=f2bf(fv.y); uf.z=f2bf(fv.z); uf.w=f2bf(fv.w);
    *(ushort4*)(gcat + (size_t)bt * 1568 + c) = uf;
  }
}

// ---------- gate=sigmoid(gacc); x=(2-g)*th+g*summary; out=LN(x). 1 wave/row ----------
__global__ __launch_bounds__(256)
void k_final(const float* __restrict__ th, const unsigned short* __restrict__ gcat,
             const float* __restrict__ gacc, const float* __restrict__ og,
             const float* __restrict__ ob, float* __restrict__ out,
             float* __restrict__ outg){
  int row = blockIdx.x * 4 + (threadIdx.x >> 6);
  int lane = threadIdx.x & 63;
  float gv = 1.f / (1.f + __expf(-gacc[row]));
  if (lane == 0) outg[row] = gv;
  const float* tr = th + (size_t)row * D768;
  const unsigned short* sr = gcat + (size_t)row * 1568 + 768;
  float x[12];
  float s = 0.f, ss = 0.f;
  #pragma unroll
  for (int k = 0; k < 3; ++k){
    int c = lane*4 + k*256;
    float4 tv = *(const float4*)(tr + c);
    ushort4 su = *(const ushort4*)(sr + c);
    float v0 = (2.f-gv)*tv.x + gv*bf2f(su.x);
    float v1 = (2.f-gv)*tv.y + gv*bf2f(su.y);
    float v2 = (2.f-gv)*tv.z + gv*bf2f(su.z);
    float v3 = (2.f-gv)*tv.w + gv*bf2f(su.w);
    x[k*4+0]=v0; x[k*4+1]=v1; x[k*4+2]=v2; x[k*4+3]=v3;
    s += v0+v1+v2+v3;
    ss += v0*v0+v1*v1+v2*v2+v3*v3;
  }
  #pragma unroll
  for (int o = 32; o; o >>= 1){ s += __shfl_xor(s, o); ss += __shfl_xor(ss, o); }
  float mean = s*(1.f/768.f), var = ss*(1.f/768.f)-mean*mean;
  float rstd = rsqrtf(var + 1e-5f);
  #pragma unroll
  for (int k = 0; k < 3; ++k){
    int c = lane*4 + k*256;
    float4 gvv = *(const float4*)(og + c);
    float4 bvv = *(const float4*)(ob + c);
    float4 ov;
    ov.x = (x[k*4+0]-mean)*rstd*gvv.x + bvv.x;
    ov.y = (x[k*4+1]-mean)*rstd*gvv.y + bvv.y;
    ov.z = (x[k*4+2]-mean)*rstd*gvv.z + bvv.z;
    ov.w = (x[k*4+3]-mean)*rstd*gvv.w + bvv.w;
    *(float4*)(out + (size_t)row * D768 + c) = ov;
  }
}

extern "C" void kernel_launch(void* const* d_in, const int* in_sizes, int n_in,
                              void* d_out, int out_size, void* d_ws, size_t ws_size,
                              hipStream_t stream){
  const float* target = (const float*)d_in[0];
  const float* support= (const float*)d_in[1];
  const void*  maskp  = d_in[2];
  const float* feat   = (const float*)d_in[3];
  const float* t_g = (const float*)d_in[4];
  const float* t_b = (const float*)d_in[5];
  const float* s_g = (const float*)d_in[6];
  const float* s_b = (const float*)d_in[7];
  const float* o_g = (const float*)d_in[8];
  const float* o_b = (const float*)d_in[9];
  const float* sw1 = (const float*)d_in[10];
  const float* sb1 = (const float*)d_in[11];
  const float* sw2 = (const float*)d_in[12];
  const float* sb2 = (const float*)d_in[13];
  const float* gw1 = (const float*)d_in[14];
  const float* gb1 = (const float*)d_in[15];
  const float* gw2 = (const float*)d_in[16];
  const float* gb2 = (const float*)d_in[17];

  char* wsb = (char*)d_ws;
  size_t off = 0;
  auto alloc = [&](size_t bytes)->void*{
    void* p = wsb + off; off += (bytes + 255) & ~(size_t)255; return p;
  };
  float* th            = (float*)alloc(4096ull*768*4);
  unsigned short* sh   = (unsigned short*)alloc(32768ull*768*2);
  float* tproj         = (float*)alloc(4096ull*768*4);
  unsigned short* gcat = (unsigned short*)alloc(4096ull*1568*2);
  unsigned short* WtA  = (unsigned short*)alloc(768ull*768*2);
  unsigned short* WtB  = (unsigned short*)alloc(768ull*768*2);
  unsigned short* WtG  = (unsigned short*)alloc(768ull*1568*2);
  float* scores        = (float*)alloc(32768ull*4);
  float* gacc          = (float*)alloc(4096ull*4);
  int*   flag          = (int*)alloc(256);

  float* outm = (float*)d_out;       // (B,T,D)
  float* outg = outm + 4096ull*768;  // (B,T)

  // init + maskdet + weight transposes + target LN
  k_pre<<<3480, 256, 0, stream>>>(target, t_g, t_b, th, gcat,
                                  sw1, gw1, WtA, WtB, WtG,
                                  scores, sb2, gacc, gb2,
                                  (const unsigned char*)maskp, flag);
  // support LN (BW-bound) overlapped with tproj GEMM (latency-bound)
  k_slntp<<<8576, 256, 0, stream>>>(support, s_g, s_b, sh, gcat, WtA, tproj);
  // scores += rowsum(gelu(sh@W1b + tproj + b1) * w2)   (256x128 tile, 768 blocks, ntn=6)
  k_gemm8<<<768, 512, 0, stream>>>(sh, 768, WtB, 768, 24, 6,
                                   tproj, sb1, sw2, scores);
  // masked softmax + summary -> gcat[:, 768:1568]
  k_smx<<<4096, 192, 0, stream>>>(scores, maskp, flag, sh, feat, gcat);
  // gate_acc += rowsum(gelu(gcat@gW1 + gb1) * gw2)   (64x64 tile, 768 blocks, ntn=12)
  k_gemm8g<<<768, 512, 0, stream>>>(gcat, 1568, WtG, 1568, 49, 12,
                                    gb1, gw2, gacc);
  k_final<<<1024, 256, 0, stream>>>(th, gcat, gacc, o_g, o_b, outm, outg);
}